// Round 9
// baseline (643.856 us; speedup 1.0000x reference)
//
#include <hip/hip_runtime.h>
#include <stdint.h>

// ---------------------------------------------------------------------------
// MHA block, round 15.
// r14 post-mortem: fused coop version FAILED correctness (absmax 4.09).
// Suspects: (a) cg grid.sync under graph capture silently broken;
// (b) release-only __threadfence (no acquire after sync).  Index math and
// attn pairing re-audited clean (vmcnt retires in issue order -> the
// paired call's vmcnt(4) is safe).
// Change vs r14: SAME fusion, explicit mechanisms:
//  * no cooperative launch, no cg::sync.  Own arrive-and-spin barrier on
//    device-scope atomics (G16-sanctioned), counters in ws+64MB, zeroed
//    per launch by hipMemsetAsync (capture-legal).
//  * fences both sides: syncthreads (drains vmcnt) -> threadfence (release,
//    L2 wb) -> atomic arrive/spin -> syncthreads -> threadfence (acquire).
//  * residency: K1 384 blk @48KB (cap 768), K2 768 blk @40KB (cap 1024) --
//    fully resident with margin, spin cannot deadlock.
// Kernel bodies identical to r14 (r7/r10-proven cores).
// ---------------------------------------------------------------------------

typedef unsigned short ushort_t;
typedef __attribute__((ext_vector_type(8))) __bf16 bf16x8;   // MFMA A/B operand
typedef __attribute__((ext_vector_type(4))) float floatx4;   // MFMA C/D operand

#define EMBED 1024
#define SEQ   2048
#define NH    16
#define DH    64
#define QK_SCALE 0.18033688011112042f   // 0.125 * log2(e)

// fp32 -> bf16 round-to-nearest-even (finite inputs)
__device__ inline ushort_t f2b(float x) {
  unsigned u = __float_as_uint(x);
  u += 0x7FFFu + ((u >> 16) & 1u);
  return (ushort_t)(u >> 16);
}

// pack bf16(a) | bf16(b)<<16 with +0x8000 round: 2 add + 1 perm
__device__ inline unsigned pk2(float a, float b) {
  unsigned ua = __float_as_uint(a) + 0x8000u;
  unsigned ub = __float_as_uint(b) + 0x8000u;
  return __builtin_amdgcn_perm(ub, ua, 0x07060302u);   // [a2,a3,b2,b3]
}

// async global->LDS, 16B/lane; LDS dest = wave-uniform base (+ lane*16 by HW)
__device__ inline void gl_lds16(const ushort_t* g, ushort_t* l) {
  __builtin_amdgcn_global_load_lds(
      (const __attribute__((address_space(1))) unsigned int*)g,
      (__attribute__((address_space(3))) unsigned int*)l, 16, 0, 0);
}

// ---------------------------------------------------------------------------
// Grid barrier: arrive-and-spin on a device-scope atomic counter.  Requires
// all blocks resident (grid <= capacity, exclusive GPU).  Counter zeroed by
// host memset each launch.  syncthreads drains each wave's vmcnt (compiler
// emits full waitcnt before s_barrier); threadfence release writes back L2;
// acquire side invalidates before cross-block reads.
// ---------------------------------------------------------------------------
__device__ inline void grid_arrive_wait(unsigned* cnt, unsigned target) {
  __syncthreads();
  __threadfence();   // release: my block's writes -> visible agent-wide
  if (threadIdx.x == 0) {
    __hip_atomic_fetch_add(cnt, 1u, __ATOMIC_ACQ_REL, __HIP_MEMORY_SCOPE_AGENT);
    while (__hip_atomic_load(cnt, __ATOMIC_ACQUIRE, __HIP_MEMORY_SCOPE_AGENT)
           < target)
      __builtin_amdgcn_s_sleep(2);
  }
  __syncthreads();
  __threadfence();   // acquire: invalidate caches before reading others' data
}

// ---------------------------------------------------------------------------
// Shared epilogue: write one 16x16 C subtile from C-layout accumulator.
//   mode 0 = bf16 row-major, 1 = f32 row-major, 2 = bf16 into VpT[b][h][d][s]
// ---------------------------------------------------------------------------
__device__ inline void store_sub(char* __restrict__ Cv, const int mode,
                                 const int ldc, const int row, const int col,
                                 const floatx4& acc) {
  if (mode == 0) {
    ushort_t* C = (ushort_t*)Cv;
#pragma unroll
    for (int r = 0; r < 4; ++r)
      C[(size_t)(row + r) * ldc + col] = f2b(acc[r]);
  } else if (mode == 1) {
    float* C = (float*)Cv;
#pragma unroll
    for (int r = 0; r < 4; ++r)
      C[(size_t)(row + r) * ldc + col] = acc[r];
  } else {
    // VpT[b][h][d][s]: r -> consecutive s, one 8B store
    ushort_t* C = (ushort_t*)Cv;
    const int b = row >> 11, s = row & 2047;
    const int h = col >> 6, d = col & 63;
    uint2 pk;
    pk.x = pk2(acc[0], acc[1]);
    pk.y = pk2(acc[2], acc[3]);
    *(uint2*)&C[(size_t)((b * NH + h) * DH + d) * SEQ + s] = pk;
  }
}

// ---------------------------------------------------------------------------
// 512-thread GEMM core (r7-exact): C[m,n] = sum_k A[m,k]*W[n,k], K=1024.
// BM=256, BN=128, BK=64; 8 waves as 4m x 2n, each wave 64x64 (4x4 subtiles).
// Single-buffer LDS 48KB, 2-barrier drain loop (known 55-57us on qkv).
// ---------------------------------------------------------------------------
__device__ inline void gemm512_core(const ushort_t* __restrict__ A,
                                    const ushort_t* __restrict__ W,
                                    char* __restrict__ Cv, const int mode,
                                    const int ldc, const int m0, const int n0) {
  __shared__ ushort_t As[32 * 512];   // 256 x 64 bf16, fragment-ordered
  __shared__ ushort_t Bs[16 * 512];   // 128 x 64
  const int tid  = threadIdx.x;
  const int lane = tid & 63;
  const int wid  = tid >> 6;          // 0..7
  const int lm   = lane & 15;
  const int quad = lane >> 4;
  const int wm   = wid >> 1;          // 0..3
  const int wn   = wid & 1;           // 0..1

  floatx4 zero = {0.f, 0.f, 0.f, 0.f};
  floatx4 acc[4][4];
#pragma unroll
  for (int i = 0; i < 4; ++i)
#pragma unroll
    for (int j = 0; j < 4; ++j) acc[i][j] = zero;

  for (int k0 = 0; k0 < EMBED; k0 += 64) {
    __syncthreads();
#pragma unroll
    for (int u = 0; u < 6; ++u) {
      const int c   = wid * 6 + u;     // 0..47, wave-uniform
      const int cb  = c & 31;          // chunk within its array
      const int sub = cb >> 1;
      const int kc  = (cb & 1) * 32 + quad * 8;
      if (c < 32)
        gl_lds16(A + (size_t)(m0 + sub * 16 + lm) * EMBED + k0 + kc, &As[cb * 512]);
      else
        gl_lds16(W + (size_t)(n0 + sub * 16 + lm) * EMBED + k0 + kc, &Bs[cb * 512]);
    }
    __syncthreads();   // vmcnt drain -> LDS visible

#pragma unroll
    for (int ks = 0; ks < 2; ++ks) {
      bf16x8 a[4], b[4];
#pragma unroll
      for (int i = 0; i < 4; ++i)
        a[i] = *(const bf16x8*)&As[((wm * 4 + i) * 2 + ks) * 512 + lane * 8];
#pragma unroll
      for (int j = 0; j < 4; ++j)
        b[j] = *(const bf16x8*)&Bs[((wn * 4 + j) * 2 + ks) * 512 + lane * 8];
#pragma unroll
      for (int i = 0; i < 4; ++i)
#pragma unroll
        for (int j = 0; j < 4; ++j)
          acc[i][j] = __builtin_amdgcn_mfma_f32_16x16x32_bf16(a[i], b[j], acc[i][j], 0, 0, 0);
    }
  }

#pragma unroll
  for (int i = 0; i < 4; ++i) {
    const int row = m0 + wm * 64 + i * 16 + quad * 4;
#pragma unroll
    for (int j = 0; j < 4; ++j)
      store_sub(Cv, mode, ldc, row, n0 + wn * 64 + j * 16 + lm, acc[i][j]);
  }
}

// ---------------------------------------------------------------------------
// Fused kernel 1: cvt (grid-stride) -> grid barrier -> qkv (r7 core).
// Grid 384 x 512 (48KB LDS -> 3/CU capacity 768: fully resident).
// ---------------------------------------------------------------------------
struct FusedA {
  const float*    src[16];
  ushort_t*       dst[16];
  float           scale[16];
  const ushort_t* A[3];
  const ushort_t* W[3];
  char*           C[3];
  unsigned*       bar;
};

__global__ __launch_bounds__(512, 4) void cvt_qkv_kernel(FusedA fa) {
  // phase 1: fp32 -> bf16 convert, 384*512 = 196608 threads, 11 passes
  {
    const unsigned idx0 = blockIdx.x * 512u + threadIdx.x;
#pragma unroll 1
    for (int p = 0; p < 11; ++p) {
      const unsigned idx = p * 196608u + idx0;   // octet index, 2M total
      if (idx < 2097152u) {
        const int chunk = idx >> 17;             // 16 chunks x 131072 octets
        const unsigned off = (idx & 131071u) << 3;
        const float sc = fa.scale[chunk];
        const float4* s = (const float4*)(fa.src[chunk] + off);
        float4 f0 = s[0], f1 = s[1];
        union { ushort_t u[8]; uint4 v; } o;
        o.u[0] = f2b(f0.x * sc); o.u[1] = f2b(f0.y * sc);
        o.u[2] = f2b(f0.z * sc); o.u[3] = f2b(f0.w * sc);
        o.u[4] = f2b(f1.x * sc); o.u[5] = f2b(f1.y * sc);
        o.u[6] = f2b(f1.z * sc); o.u[7] = f2b(f1.w * sc);
        *(uint4*)(fa.dst[chunk] + off) = o.v;
      }
    }
  }
  grid_arrive_wait(fa.bar, 384u);
  // phase 2: qkv, one tile per block; linearization x + 16y + 128z (r7 order)
  const int t = blockIdx.x;            // 0..383
  const int z = t >> 7, y = (t >> 4) & 7, x = t & 15;
  gemm512_core(fa.A[z], fa.W[z], fa.C[z], z == 2 ? 2 : 0, EMBED,
               x * 256, y * 128);
}

// ---------------------------------------------------------------------------
// Attention body (r7 structure), smem-aliased to share a 40KB union.
// smem layout (ushorts): [0,4096) Qs (aliased P scratch); [4096,12288) Ks
// dbuf; [12288,20480) VTs dbuf.
// ---------------------------------------------------------------------------
__device__ void attn_body(const ushort_t* __restrict__ Qp,
                          const ushort_t* __restrict__ Kp,
                          const ushort_t* __restrict__ VpT,
                          ushort_t* __restrict__ Ob,
                          ushort_t* smem, const int L) {
  const int s8 = (L >> 5) & 7;
  const int g  = L >> 8;                 // 0..3
  const int qb = (g == 0) ? s8
               : (g == 1) ? (15 - s8)
               : (g == 2) ? (16 + s8)
                          : (31 - s8);
  const int bh = L & 31;
  const int h = bh & (NH - 1), b = bh >> 4;
  const int tid = threadIdx.x, lane = tid & 63, wid = tid >> 6;
  const int lm = lane & 15, quad = lane >> 4;
  const size_t qkbase = ((size_t)b * SEQ) * EMBED + h * DH;
  const size_t vtbase = ((size_t)(b * NH + h)) * DH * SEQ;
  ushort_t* Qs = smem;

  // Q staging: 4 chunks of 512; wave's pair c = wid*2 + u covers its 16 q.
#pragma unroll
  for (int u = 0; u < 2; ++u) {
    const int c = wid * 2 + u;
    gl_lds16(Qp + qkbase + (size_t)(qb * 64 + (c >> 1) * 16 + lm) * EMBED
                 + (c & 1) * 32 + quad * 8,
             &Qs[c * 512]);
  }
  // issue K/V for kt=0 into buf 0 (behind the Q loads)
#pragma unroll
  for (int u = 0; u < 4; ++u) {
    const int tt = wid * 4 + u;
    const int cb = tt & 7, sub = cb >> 1, half = cb & 1;
    if (tt < 8)
      gl_lds16(Kp + qkbase + (size_t)(sub * 16 + lm) * EMBED + half * 32 + quad * 8,
               &smem[4096 + cb * 512]);
    else
      gl_lds16(VpT + vtbase + (size_t)(sub * 16 + lm) * SEQ + half * 32 + quad * 8,
               &smem[12288 + cb * 512]);
  }
  // vmcnt retires in issue order: waiting to 4 outstanding covers any older
  // stores plus this wave's 2 Q loads.
  asm volatile("s_waitcnt vmcnt(4)" ::: "memory");
  bf16x8 qf[2];   // [ks]
#pragma unroll
  for (int ks = 0; ks < 2; ++ks)
    qf[ks] = *(const bf16x8*)&Qs[(wid * 2 + ks) * 512 + lane * 8];
  // Q region is now dead; reuse the wave's own 2KB slice as P scratch.
  ushort_t* pwb = &Qs[wid * 1024];

  float l_part = 0.f;
  floatx4 zero = {0.f, 0.f, 0.f, 0.f};
  floatx4 o_acc[4];
#pragma unroll
  for (int d = 0; d < 4; ++d) o_acc[d] = zero;

  for (int kt = 0; kt <= qb; ++kt) {
    const int cur = kt & 1;
    ushort_t* Kc = smem + 4096 + cur * 4096;
    ushort_t* Vc = smem + 12288 + cur * 4096;
    // my K/V[cur] loads (issued last iter / preamble) have landed by now
    asm volatile("s_waitcnt vmcnt(0)" ::: "memory");
    __syncthreads();   // all waves' cur loads landed; all done reading buf cur^1
    if (kt < qb) {
      const int kn = kt + 1;
      ushort_t* Knx = smem + 4096 + (cur ^ 1) * 4096;
      ushort_t* Vnx = smem + 12288 + (cur ^ 1) * 4096;
#pragma unroll
      for (int u = 0; u < 4; ++u) {
        const int tt = wid * 4 + u;
        const int cb = tt & 7, sub = cb >> 1, half = cb & 1;
        if (tt < 8)
          gl_lds16(Kp + qkbase + (size_t)(kn * 64 + sub * 16 + lm) * EMBED
                       + half * 32 + quad * 8,
                   &Knx[cb * 512]);
        else
          gl_lds16(VpT + vtbase + (size_t)(sub * 16 + lm) * SEQ
                       + kn * 64 + half * 32 + quad * 8,
                   &Vnx[cb * 512]);
      }
    }

    // S^T = K Q^T (log2e domain): s_acc[i], i = kk-subtile 0..3
    floatx4 s_acc[4];
#pragma unroll
    for (int i = 0; i < 4; ++i) s_acc[i] = zero;
#pragma unroll
    for (int ks = 0; ks < 2; ++ks)
#pragma unroll
      for (int i = 0; i < 4; ++i) {
        bf16x8 kf = *(const bf16x8*)&Kc[(i * 2 + ks) * 512 + lane * 8];
        s_acc[i] = __builtin_amdgcn_mfma_f32_16x16x32_bf16(kf, qf[ks], s_acc[i], 0, 0, 0);
      }

    // exp2, diagonal mask, l accumulate, pack P^T into wave-private scratch
    const bool diag = (kt == qb);   // uniform branch; last iter only
#pragma unroll
    for (int i = 0; i < 4; ++i) {
      const int sH = i >> 1;
      const int quadB = ((i & 1) << 1) | (quad >> 1);
      const int gkk = kt * 64 + i * 16 + quad * 4;
      float p[4];
#pragma unroll
      for (int r = 0; r < 4; ++r) p[r] = __builtin_amdgcn_exp2f(s_acc[i][r]);
      if (diag) {
        const int gq = qb * 64 + wid * 16 + lm;
#pragma unroll
        for (int r = 0; r < 4; ++r)
          if (gkk + r > gq) p[r] = 0.f;
      }
#pragma unroll
      for (int r = 0; r < 4; ++r) l_part += p[r];
      uint2 pk;
      pk.x = pk2(p[0], p[1]);
      pk.y = pk2(p[2], p[3]);
      *(uint2*)&pwb[sH * 512 + (quadB * 16 + lm) * 8 + ((quad & 1) << 2)] = pk;
    }
    asm volatile("s_waitcnt lgkmcnt(0)" ::: "memory");   // wave-local RAW fence

    // O^T += V^T P^T
#pragma unroll
    for (int sH = 0; sH < 2; ++sH) {
      bf16x8 pf = *(const bf16x8*)&pwb[sH * 512 + lane * 8];
#pragma unroll
      for (int d = 0; d < 4; ++d) {
        bf16x8 vf = *(const bf16x8*)&Vc[(d * 2 + sH) * 512 + lane * 8];
        o_acc[d] = __builtin_amdgcn_mfma_f32_16x16x32_bf16(vf, pf, o_acc[d], 0, 0, 0);
      }
    }
  }

  // epilogue
  {
    float l = l_part;
    l += __shfl_xor(l, 16, 64);
    l += __shfl_xor(l, 32, 64);
    const float inv_l = 1.0f / l;
    const size_t orow = qkbase + (size_t)(qb * 64 + wid * 16 + lm) * EMBED;
#pragma unroll
    for (int d = 0; d < 4; ++d) {
      uint2 pk;
      pk.x = pk2(o_acc[d][0] * inv_l, o_acc[d][1] * inv_l);
      pk.y = pk2(o_acc[d][2] * inv_l, o_acc[d][3] * inv_l);
      *(uint2*)&Ob[orow + d * 16 + quad * 4] = pk;
    }
  }
}

// ---------------------------------------------------------------------------
// O-projection core (r10 o_gemm), smem-aliased: As [0,8192), Bs [8192,12288).
// BM=128, BN=64, BK=64, 4 waves 2m x 2n, wave 64x32 (4x2 subtiles).
// ---------------------------------------------------------------------------
__device__ void o_core(const ushort_t* __restrict__ A,
                       const ushort_t* __restrict__ W,
                       float* __restrict__ C, ushort_t* smem,
                       const int bx, const int by) {
  ushort_t* As = smem;            // 128 x 64, fragment-ordered (16KB)
  ushort_t* Bs = smem + 8192;     // 64 x 64 (8KB)
  const int m0 = bx * 128, n0 = by * 64;
  const int tid  = threadIdx.x;
  const int lane = tid & 63;
  const int wid  = tid >> 6;
  const int lm   = lane & 15;
  const int quad = lane >> 4;
  const int wm   = wid >> 1;
  const int wn   = wid & 1;

  floatx4 zero = {0.f, 0.f, 0.f, 0.f};
  floatx4 acc[4][2];
#pragma unroll
  for (int i = 0; i < 4; ++i)
#pragma unroll
    for (int j = 0; j < 2; ++j) acc[i][j] = zero;

  for (int k0 = 0; k0 < EMBED; k0 += 64) {
    __syncthreads();
#pragma unroll
    for (int u = 0; u < 6; ++u) {
      const int c   = wid * 6 + u;     // 0..23, wave-uniform
      const int cb  = (c < 16) ? c : (c - 16);
      const int sub = cb >> 1;
      const int kc  = (cb & 1) * 32 + quad * 8;
      if (c < 16)
        gl_lds16(A + (size_t)(m0 + sub * 16 + lm) * EMBED + k0 + kc, &As[cb * 512]);
      else
        gl_lds16(W + (size_t)(n0 + sub * 16 + lm) * EMBED + k0 + kc, &Bs[cb * 512]);
    }
    __syncthreads();   // vmcnt drain -> LDS visible

#pragma unroll
    for (int ks = 0; ks < 2; ++ks) {
      bf16x8 a[4], b[2];
#pragma unroll
      for (int i = 0; i < 4; ++i)
        a[i] = *(const bf16x8*)&As[((wm * 4 + i) * 2 + ks) * 512 + lane * 8];
#pragma unroll
      for (int j = 0; j < 2; ++j)
        b[j] = *(const bf16x8*)&Bs[((wn * 2 + j) * 2 + ks) * 512 + lane * 8];
#pragma unroll
      for (int i = 0; i < 4; ++i)
#pragma unroll
        for (int j = 0; j < 2; ++j)
          acc[i][j] = __builtin_amdgcn_mfma_f32_16x16x32_bf16(a[i], b[j], acc[i][j], 0, 0, 0);
    }
  }

#pragma unroll
  for (int i = 0; i < 4; ++i) {
    const int row = m0 + wm * 64 + i * 16 + quad * 4;
#pragma unroll
    for (int j = 0; j < 2; ++j) {
      const int col = n0 + wn * 32 + j * 16 + lm;
#pragma unroll
      for (int r = 0; r < 4; ++r)
        C[(size_t)(row + r) * EMBED + col] = acc[i][j][r];
    }
  }
}

// ---------------------------------------------------------------------------
// Fused kernel 2: attn -> grid barrier -> o_gemm.  Grid 768 x 256 (40KB ->
// 4/CU capacity 1024: fully resident).  Blocks <256 run attn tile pair
// (L=r then L=256+r); blocks >=256 run L=256+r.  With round-robin placement
// the 3 blocks on a CU total 66 iters (17 + 17+s + 32-s), uniform.
// Phase B: blocks <512 do o_gemm tile (r&31, r>>5).
// ---------------------------------------------------------------------------
struct FusedB {
  const ushort_t* Qp;
  const ushort_t* Kp;
  const ushort_t* VpT;
  ushort_t*       Ob;
  const ushort_t* Wob;
  float*          out;
  unsigned*       bar;
};

__global__ __launch_bounds__(256, 4) void attn_o_kernel(FusedB fb) {
  __shared__ ushort_t smem[20480];   // 40KB union: attn 40KB / o_core 24KB
  const int r = blockIdx.x;          // 0..767
  if (r < 256) {
    attn_body(fb.Qp, fb.Kp, fb.VpT, fb.Ob, smem, r);         // g0 (qb = s)
    __syncthreads();                                          // smem reuse
    attn_body(fb.Qp, fb.Kp, fb.VpT, fb.Ob, smem, 256 + r);   // g1 (15 - s)
  } else {
    attn_body(fb.Qp, fb.Kp, fb.VpT, fb.Ob, smem, 256 + r);   // g2 / g3
  }
  grid_arrive_wait(fb.bar, 768u);
  if (r < 512)
    o_core(fb.Ob, fb.Wob, fb.out, smem, r & 31, r >> 5);
}

// ---------------------------------------------------------------------------
// launch
// ---------------------------------------------------------------------------
extern "C" void kernel_launch(void* const* d_in, const int* in_sizes, int n_in,
                              void* d_out, int out_size, void* d_ws, size_t ws_size,
                              hipStream_t stream) {
  // setup_inputs() order: key, query, value, mask, Wq, Wk, Wv, Wo
  const float* key   = (const float*)d_in[0];
  const float* query = (const float*)d_in[1];
  const float* value = (const float*)d_in[2];
  // d_in[3] = static causal tril, handled analytically
  const float* Wq = (const float*)d_in[4];
  const float* Wk = (const float*)d_in[5];
  const float* Wv = (const float*)d_in[6];
  const float* Wo = (const float*)d_in[7];

  char* ws = (char*)d_ws;
  const size_t MB = 1024 * 1024;
  ushort_t* Xk  = (ushort_t*)(ws + 0 * MB);    // key   bf16 [4096][1024]
  ushort_t* Xq  = (ushort_t*)(ws + 8 * MB);    // query bf16
  ushort_t* Xv  = (ushort_t*)(ws + 16 * MB);   // value bf16
  ushort_t* Wqb = (ushort_t*)(ws + 24 * MB);   // pre-scaled by 0.125*log2e
  ushort_t* Wkb = (ushort_t*)(ws + 26 * MB);
  ushort_t* Wvb = (ushort_t*)(ws + 28 * MB);
  ushort_t* Wob = (ushort_t*)(ws + 30 * MB);
  ushort_t* Qp  = (ushort_t*)(ws + 32 * MB);   // projected Q (log2e-scaled)
  ushort_t* Kp  = (ushort_t*)(ws + 40 * MB);
  ushort_t* VpT = (ushort_t*)(ws + 48 * MB);   // [b][h][64][2048]
  ushort_t* Ob  = (ushort_t*)(ws + 56 * MB);   // attention out bf16
  unsigned* bar = (unsigned*)(ws + 64 * MB);   // [0]=K1 counter, [16]=K2

  hipMemsetAsync(bar, 0, 128, stream);         // zero barrier counters

  FusedA fa;
  const size_t CE = 1048576;
  for (int c = 0; c < 16; ++c) fa.scale[c] = 1.0f;
  for (int c = 0; c < 4; ++c) { fa.src[c]     = key   + c * CE; fa.dst[c]     = Xk + c * CE; }
  for (int c = 0; c < 4; ++c) { fa.src[4 + c] = query + c * CE; fa.dst[4 + c] = Xq + c * CE; }
  for (int c = 0; c < 4; ++c) { fa.src[8 + c] = value + c * CE; fa.dst[8 + c] = Xv + c * CE; }
  fa.src[12] = Wq; fa.dst[12] = Wqb; fa.scale[12] = QK_SCALE;
  fa.src[13] = Wk; fa.dst[13] = Wkb;
  fa.src[14] = Wv; fa.dst[14] = Wvb;
  fa.src[15] = Wo; fa.dst[15] = Wob;
  fa.A[0] = Xq; fa.W[0] = Wqb; fa.C[0] = (char*)Qp;
  fa.A[1] = Xk; fa.W[1] = Wkb; fa.C[1] = (char*)Kp;
  fa.A[2] = Xv; fa.W[2] = Wvb; fa.C[2] = (char*)VpT;   // z=2 writes transposed
  fa.bar = bar;

  cvt_qkv_kernel<<<384, 512, 0, stream>>>(fa);

  FusedB fb;
  fb.Qp = Qp; fb.Kp = Kp; fb.VpT = VpT; fb.Ob = Ob;
  fb.Wob = Wob; fb.out = (float*)d_out;
  fb.bar = bar + 16;

  attn_o_kernel<<<768, 256, 0, stream>>>(fb);
}

// Round 10
// 257.770 us; speedup vs baseline: 2.4978x; 2.4978x over previous
//
#include <hip/hip_runtime.h>
#include <stdint.h>

// ---------------------------------------------------------------------------
// MHA block, round 16.
// r15 post-mortem: manual-barrier fusion PASSED but 2.7x SLOWER (attn_o
// 299us; MfmaUtil 3.5 / HBM 2.1 / VALU 6.4 -- machine idle).  Mechanism:
// 768 spinning thread-0s doing agent-scope ACQUIRE loads invalidate caches
// continuously, starving the still-computing attn blocks.  Fusion (both
// variants) is now a measured dead end -> revert to r11 4-kernel structure.
// This round (one variable): qkv FILL/BALANCE.  r11 qkv = 384 8-wave blocks
// on 256 CUs -> half the CUs run 2 tiles, half run 1 (idle ~half the phase).
// Keep the r7 core schedule; BN 128->64: grid (16,16,3) = 768 blocks =
// exactly 3 blocks/CU balanced, 24 waves/CU, LDS 40KB.  Per-wave acc 4x2,
// 5 staging chunks + 16 MFMA per K-step.  Extra A re-reads are L3-absorbed.
// Predicted: qkv 57.4 -> ~42-47us, FETCH ~37MB, WRITE ~24.6MB (if WRITE
// balloons like r9 the amplification is BM-tied -> revert next round).
// cvt/attn/o_gemm identical to r11.
// ---------------------------------------------------------------------------

typedef unsigned short ushort_t;
typedef __attribute__((ext_vector_type(8))) __bf16 bf16x8;   // MFMA A/B operand
typedef __attribute__((ext_vector_type(4))) float floatx4;   // MFMA C/D operand

#define EMBED 1024
#define SEQ   2048
#define NH    16
#define DH    64
#define QK_SCALE 0.18033688011112042f   // 0.125 * log2(e)

// fp32 -> bf16 round-to-nearest-even (finite inputs)
__device__ inline ushort_t f2b(float x) {
  unsigned u = __float_as_uint(x);
  u += 0x7FFFu + ((u >> 16) & 1u);
  return (ushort_t)(u >> 16);
}

// pack bf16(a) | bf16(b)<<16 with +0x8000 round: 2 add + 1 perm
__device__ inline unsigned pk2(float a, float b) {
  unsigned ua = __float_as_uint(a) + 0x8000u;
  unsigned ub = __float_as_uint(b) + 0x8000u;
  return __builtin_amdgcn_perm(ub, ua, 0x07060302u);   // [a2,a3,b2,b3]
}

// async global->LDS, 16B/lane; LDS dest = wave-uniform base (+ lane*16 by HW)
__device__ inline void gl_lds16(const ushort_t* g, ushort_t* l) {
  __builtin_amdgcn_global_load_lds(
      (const __attribute__((address_space(1))) unsigned int*)g,
      (__attribute__((address_space(3))) unsigned int*)l, 16, 0, 0);
}

// ---------------------------------------------------------------------------
// fp32 -> bf16 bulk convert, with per-chunk scale (folds QK scale into Wq)
// ---------------------------------------------------------------------------
struct CvtArgs {
  const float* src[16];
  ushort_t*    dst[16];
  float        scale[16];
};

__global__ __launch_bounds__(256) void cvt_kernel(CvtArgs a) {
  const int chunk = blockIdx.x >> 9;
  const int off = ((blockIdx.x & 511) << 11) + (threadIdx.x << 3);
  const float sc = a.scale[chunk];
  const float4* s = (const float4*)(a.src[chunk] + off);
  float4 f0 = s[0], f1 = s[1];
  union { ushort_t u[8]; uint4 v; } o;
  o.u[0] = f2b(f0.x * sc); o.u[1] = f2b(f0.y * sc);
  o.u[2] = f2b(f0.z * sc); o.u[3] = f2b(f0.w * sc);
  o.u[4] = f2b(f1.x * sc); o.u[5] = f2b(f1.y * sc);
  o.u[6] = f2b(f1.z * sc); o.u[7] = f2b(f1.w * sc);
  *(uint4*)(a.dst[chunk] + off) = o.v;
}

// ---------------------------------------------------------------------------
// Shared epilogue: write one 16x16 C subtile from C-layout accumulator.
//   mode 0 = bf16 row-major, 1 = f32 row-major, 2 = bf16 into VpT[b][h][d][s]
// ---------------------------------------------------------------------------
__device__ inline void store_sub(char* __restrict__ Cv, const int mode,
                                 const int ldc, const int row, const int col,
                                 const floatx4& acc) {
  if (mode == 0) {
    ushort_t* C = (ushort_t*)Cv;
#pragma unroll
    for (int r = 0; r < 4; ++r)
      C[(size_t)(row + r) * ldc + col] = f2b(acc[r]);
  } else if (mode == 1) {
    float* C = (float*)Cv;
#pragma unroll
    for (int r = 0; r < 4; ++r)
      C[(size_t)(row + r) * ldc + col] = acc[r];
  } else {
    // VpT[b][h][d][s]: r -> consecutive s, one 8B store
    ushort_t* C = (ushort_t*)Cv;
    const int b = row >> 11, s = row & 2047;
    const int h = col >> 6, d = col & 63;
    uint2 pk;
    pk.x = pk2(acc[0], acc[1]);
    pk.y = pk2(acc[2], acc[3]);
    *(uint2*)&C[(size_t)((b * NH + h) * DH + d) * SEQ + s] = pk;
  }
}

// ---------------------------------------------------------------------------
// 512-thread GEMM core: C[m,n] = sum_k A[m,k]*W[n,k], K=1024 fixed.
// r16: BM=256, BN=64, BK=64; 8 waves as 4m x 2n, each wave 64x32 (4x2
// subtiles).  Same 2-barrier schedule / staging / fragment layout as r7;
// LDS 40KB (As 32KB + Bs 8KB).  Grid supplies 768 blocks = 3/CU balanced.
// ---------------------------------------------------------------------------
__device__ inline void gemm512_core(const ushort_t* __restrict__ A,
                                    const ushort_t* __restrict__ W,
                                    char* __restrict__ Cv, const int mode,
                                    const int ldc, const int m0, const int n0) {
  __shared__ ushort_t As[32 * 512];   // 256 x 64 bf16, fragment-ordered
  __shared__ ushort_t Bs[8 * 512];    // 64 x 64
  const int tid  = threadIdx.x;
  const int lane = tid & 63;
  const int wid  = tid >> 6;          // 0..7
  const int lm   = lane & 15;
  const int quad = lane >> 4;
  const int wm   = wid >> 1;          // 0..3
  const int wn   = wid & 1;           // 0..1

  floatx4 zero = {0.f, 0.f, 0.f, 0.f};
  floatx4 acc[4][2];
#pragma unroll
  for (int i = 0; i < 4; ++i)
#pragma unroll
    for (int j = 0; j < 2; ++j) acc[i][j] = zero;

  for (int k0 = 0; k0 < EMBED; k0 += 64) {
    __syncthreads();
#pragma unroll
    for (int u = 0; u < 5; ++u) {
      const int c = wid * 5 + u;       // 0..39, wave-uniform
      if (c < 32) {
        const int sub = c >> 1;
        const int kc  = (c & 1) * 32 + quad * 8;
        gl_lds16(A + (size_t)(m0 + sub * 16 + lm) * EMBED + k0 + kc, &As[c * 512]);
      } else {
        const int cb  = c - 32;        // 0..7
        const int sub = cb >> 1;
        const int kc  = (cb & 1) * 32 + quad * 8;
        gl_lds16(W + (size_t)(n0 + sub * 16 + lm) * EMBED + k0 + kc, &Bs[cb * 512]);
      }
    }
    __syncthreads();   // vmcnt drain -> LDS visible

#pragma unroll
    for (int ks = 0; ks < 2; ++ks) {
      bf16x8 a[4], b[2];
#pragma unroll
      for (int i = 0; i < 4; ++i)
        a[i] = *(const bf16x8*)&As[((wm * 4 + i) * 2 + ks) * 512 + lane * 8];
#pragma unroll
      for (int j = 0; j < 2; ++j)
        b[j] = *(const bf16x8*)&Bs[((wn * 2 + j) * 2 + ks) * 512 + lane * 8];
#pragma unroll
      for (int i = 0; i < 4; ++i)
#pragma unroll
        for (int j = 0; j < 2; ++j)
          acc[i][j] = __builtin_amdgcn_mfma_f32_16x16x32_bf16(a[i], b[j], acc[i][j], 0, 0, 0);
    }
  }

#pragma unroll
  for (int i = 0; i < 4; ++i) {
    const int row = m0 + wm * 64 + i * 16 + quad * 4;
#pragma unroll
    for (int j = 0; j < 2; ++j)
      store_sub(Cv, mode, ldc, row, n0 + wn * 32 + j * 16 + lm, acc[i][j]);
  }
}

struct QkvArgs {
  const ushort_t* A[3];
  const ushort_t* W[3];
  char*           C[3];
};

// grid (16,16,3): consecutive x share the y W-slab; A re-reads across the
// y-sweep are L3-absorbed (A = 8MB/z << 256MB).
__global__ __launch_bounds__(512, 4) void qkv_gemm(QkvArgs q) {
  const int z = blockIdx.z;
  gemm512_core(q.A[z], q.W[z], q.C[z], z == 2 ? 2 : 0, EMBED,
               blockIdx.x * 256, blockIdx.y * 64);
}

// ---------------------------------------------------------------------------
// O-projection GEMM (r10): BM=128, BN=64, BK=64, 256 thr (4 waves 2m x 2n,
// each wave 64x32 = 4x2 subtiles).  Grid (32,16) = 512 blocks = 2 blocks/CU,
// 8 waves/CU in 2 independent barrier domains.  LDS 24KB.
// ---------------------------------------------------------------------------
__global__ __launch_bounds__(256, 4) void o_gemm(const ushort_t* __restrict__ A,
                                                 const ushort_t* __restrict__ W,
                                                 float* __restrict__ C) {
  __shared__ ushort_t As[16 * 512];   // 128 x 64, fragment-ordered
  __shared__ ushort_t Bs[8 * 512];    // 64 x 64
  const int m0 = blockIdx.x * 128, n0 = blockIdx.y * 64;
  const int tid  = threadIdx.x;
  const int lane = tid & 63;
  const int wid  = tid >> 6;          // 0..3
  const int lm   = lane & 15;
  const int quad = lane >> 4;
  const int wm   = wid >> 1;          // 0..1
  const int wn   = wid & 1;           // 0..1

  floatx4 zero = {0.f, 0.f, 0.f, 0.f};
  floatx4 acc[4][2];
#pragma unroll
  for (int i = 0; i < 4; ++i)
#pragma unroll
    for (int j = 0; j < 2; ++j) acc[i][j] = zero;

  for (int k0 = 0; k0 < EMBED; k0 += 64) {
    __syncthreads();
#pragma unroll
    for (int u = 0; u < 6; ++u) {
      const int c   = wid * 6 + u;     // 0..23, wave-uniform
      const int cb  = (c < 16) ? c : (c - 16);
      const int sub = cb >> 1;
      const int kc  = (cb & 1) * 32 + quad * 8;
      if (c < 16)
        gl_lds16(A + (size_t)(m0 + sub * 16 + lm) * EMBED + k0 + kc, &As[cb * 512]);
      else
        gl_lds16(W + (size_t)(n0 + sub * 16 + lm) * EMBED + k0 + kc, &Bs[cb * 512]);
    }
    __syncthreads();   // vmcnt drain -> LDS visible

#pragma unroll
    for (int ks = 0; ks < 2; ++ks) {
      bf16x8 a[4], b[2];
#pragma unroll
      for (int i = 0; i < 4; ++i)
        a[i] = *(const bf16x8*)&As[((wm * 4 + i) * 2 + ks) * 512 + lane * 8];
#pragma unroll
      for (int j = 0; j < 2; ++j)
        b[j] = *(const bf16x8*)&Bs[((wn * 2 + j) * 2 + ks) * 512 + lane * 8];
#pragma unroll
      for (int i = 0; i < 4; ++i)
#pragma unroll
        for (int j = 0; j < 2; ++j)
          acc[i][j] = __builtin_amdgcn_mfma_f32_16x16x32_bf16(a[i], b[j], acc[i][j], 0, 0, 0);
    }
  }

#pragma unroll
  for (int i = 0; i < 4; ++i) {
    const int row = m0 + wm * 64 + i * 16 + quad * 4;
#pragma unroll
    for (int j = 0; j < 2; ++j) {
      const int col = n0 + wn * 32 + j * 16 + lm;
#pragma unroll
      for (int r = 0; r < 4; ++r)
        C[(size_t)(row + r) * EMBED + col] = acc[i][j][r];
    }
  }
}

// ---------------------------------------------------------------------------
// Causal flash attention, S^T formulation, fixed-shift softmax, K/V dbuf.
// Grid 1024 x 256thr (4 waves).  Block = 64 q-cols of one (b,h); wave owns
// 16 q.  KT=64.  One barrier per iter; next K/V tile's global_load_lds
// issued right after the barrier, landing during compute.
// LDS 40KB -> 4 blocks/CU (16 waves/CU, 4/SIMD from 4 independent blocks).
// qb map: slot s=(L>>5)&7, group g=L>>8: {s, 15-s, 16+s, 31-s} -> the 4
// blocks sharing a CU under round-robin dispatch sum to 66 iters, uniform.
// bh stays in L&31 -> bh%8 == L%8 pins each head's K/V to one XCD L2
// (4 heads x 512KB = 2MB < 4MB L2).
// ---------------------------------------------------------------------------
__global__ __launch_bounds__(256, 4) void attn_kernel(const ushort_t* __restrict__ Qp,
                                                      const ushort_t* __restrict__ Kp,
                                                      const ushort_t* __restrict__ VpT,
                                                      ushort_t* __restrict__ Ob) {
  __shared__ ushort_t Qs[8 * 512];       // 64 q x 64 d; aliased as P scratch
  __shared__ ushort_t Ks[2][8 * 512];    // dbuf: 64 kk x 64 d
  __shared__ ushort_t VTs[2][8 * 512];   // dbuf: 64 d x 64 kk
  const int L = blockIdx.x;              // 0..1023
  const int s8 = (L >> 5) & 7;
  const int g  = L >> 8;                 // 0..3
  const int qb = (g == 0) ? s8
               : (g == 1) ? (15 - s8)
               : (g == 2) ? (16 + s8)
                          : (31 - s8);
  const int bh = L & 31;
  const int h = bh & (NH - 1), b = bh >> 4;
  const int tid = threadIdx.x, lane = tid & 63, wid = tid >> 6;
  const int lm = lane & 15, quad = lane >> 4;
  const size_t qkbase = ((size_t)b * SEQ) * EMBED + h * DH;
  const size_t vtbase = ((size_t)(b * NH + h)) * DH * SEQ;

  // Q staging: 4 chunks of 512; wave's pair c = wid*2 + u covers its 16 q.
#pragma unroll
  for (int u = 0; u < 2; ++u) {
    const int c = wid * 2 + u;
    gl_lds16(Qp + qkbase + (size_t)(qb * 64 + (c >> 1) * 16 + lm) * EMBED
                 + (c & 1) * 32 + quad * 8,
             &Qs[c * 512]);
  }
  // issue K/V for kt=0 into buf 0 (behind the Q loads)
#pragma unroll
  for (int u = 0; u < 4; ++u) {
    const int t = wid * 4 + u;
    const int cb = t & 7, sub = cb >> 1, half = cb & 1;
    if (t < 8)
      gl_lds16(Kp + qkbase + (size_t)(sub * 16 + lm) * EMBED + half * 32 + quad * 8,
               &Ks[0][cb * 512]);
    else
      gl_lds16(VpT + vtbase + (size_t)(sub * 16 + lm) * SEQ + half * 32 + quad * 8,
               &VTs[0][cb * 512]);
  }
  asm volatile("s_waitcnt vmcnt(4)" ::: "memory");   // my Q chunks landed
  bf16x8 qf[2];   // [ks]
#pragma unroll
  for (int ks = 0; ks < 2; ++ks)
    qf[ks] = *(const bf16x8*)&Qs[(wid * 2 + ks) * 512 + lane * 8];
  // Q region is now dead; reuse the wave's own 2KB slice as P scratch.
  ushort_t* pwb = &Qs[wid * 1024];

  float l_part = 0.f;
  floatx4 zero = {0.f, 0.f, 0.f, 0.f};
  floatx4 o_acc[4];
#pragma unroll
  for (int d = 0; d < 4; ++d) o_acc[d] = zero;

  for (int kt = 0; kt <= qb; ++kt) {
    const int cur = kt & 1;
    // my K/V[cur] loads (issued last iter / preamble) have landed by now
    asm volatile("s_waitcnt vmcnt(0)" ::: "memory");
    __syncthreads();   // all waves' cur loads landed; all done reading buf cur^1
    if (kt < qb) {
      const int kn = kt + 1;
#pragma unroll
      for (int u = 0; u < 4; ++u) {
        const int t = wid * 4 + u;
        const int cb = t & 7, sub = cb >> 1, half = cb & 1;
        if (t < 8)
          gl_lds16(Kp + qkbase + (size_t)(kn * 64 + sub * 16 + lm) * EMBED
                       + half * 32 + quad * 8,
                   &Ks[cur ^ 1][cb * 512]);
        else
          gl_lds16(VpT + vtbase + (size_t)(sub * 16 + lm) * SEQ
                       + kn * 64 + half * 32 + quad * 8,
                   &VTs[cur ^ 1][cb * 512]);
      }
    }

    // S^T = K Q^T (log2e domain): s_acc[i], i = kk-subtile 0..3
    floatx4 s_acc[4];
#pragma unroll
    for (int i = 0; i < 4; ++i) s_acc[i] = zero;
#pragma unroll
    for (int ks = 0; ks < 2; ++ks)
#pragma unroll
      for (int i = 0; i < 4; ++i) {
        bf16x8 kf = *(const bf16x8*)&Ks[cur][(i * 2 + ks) * 512 + lane * 8];
        s_acc[i] = __builtin_amdgcn_mfma_f32_16x16x32_bf16(kf, qf[ks], s_acc[i], 0, 0, 0);
      }

    // exp2, diagonal mask, l accumulate, pack P^T into wave-private scratch
    const bool diag = (kt == qb);   // uniform branch; last iter only
#pragma unroll
    for (int i = 0; i < 4; ++i) {
      const int sH = i >> 1;
      const int quadB = ((i & 1) << 1) | (quad >> 1);
      const int gkk = kt * 64 + i * 16 + quad * 4;
      float p[4];
#pragma unroll
      for (int r = 0; r < 4; ++r) p[r] = __builtin_amdgcn_exp2f(s_acc[i][r]);
      if (diag) {
        const int gq = qb * 64 + wid * 16 + lm;
#pragma unroll
        for (int r = 0; r < 4; ++r)
          if (gkk + r > gq) p[r] = 0.f;
      }
#pragma unroll
      for (int r = 0; r < 4; ++r) l_part += p[r];
      uint2 pk;
      pk.x = pk2(p[0], p[1]);
      pk.y = pk2(p[2], p[3]);
      *(uint2*)&pwb[sH * 512 + (quadB * 16 + lm) * 8 + ((quad & 1) << 2)] = pk;
    }
    asm volatile("s_waitcnt lgkmcnt(0)" ::: "memory");   // wave-local RAW fence

    // O^T += V^T P^T
#pragma unroll
    for (int sH = 0; sH < 2; ++sH) {
      bf16x8 pf = *(const bf16x8*)&pwb[sH * 512 + lane * 8];
#pragma unroll
      for (int d = 0; d < 4; ++d) {
        bf16x8 vf = *(const bf16x8*)&VTs[cur][(d * 2 + sH) * 512 + lane * 8];
        o_acc[d] = __builtin_amdgcn_mfma_f32_16x16x32_bf16(vf, pf, o_acc[d], 0, 0, 0);
      }
    }
  }

  // epilogue
  {
    float l = l_part;
    l += __shfl_xor(l, 16, 64);
    l += __shfl_xor(l, 32, 64);
    const float inv_l = 1.0f / l;
    const size_t orow = qkbase + (size_t)(qb * 64 + wid * 16 + lm) * EMBED;
#pragma unroll
    for (int d = 0; d < 4; ++d) {
      uint2 pk;
      pk.x = pk2(o_acc[d][0] * inv_l, o_acc[d][1] * inv_l);
      pk.y = pk2(o_acc[d][2] * inv_l, o_acc[d][3] * inv_l);
      *(uint2*)&Ob[orow + d * 16 + quad * 4] = pk;
    }
  }
}

// ---------------------------------------------------------------------------
// launch
// ---------------------------------------------------------------------------
extern "C" void kernel_launch(void* const* d_in, const int* in_sizes, int n_in,
                              void* d_out, int out_size, void* d_ws, size_t ws_size,
                              hipStream_t stream) {
  // setup_inputs() order: key, query, value, mask, Wq, Wk, Wv, Wo
  const float* key   = (const float*)d_in[0];
  const float* query = (const float*)d_in[1];
  const float* value = (const float*)d_in[2];
  // d_in[3] = static causal tril, handled analytically
  const float* Wq = (const float*)d_in[4];
  const float* Wk = (const float*)d_in[5];
  const float* Wv = (const float*)d_in[6];
  const float* Wo = (const float*)d_in[7];

  char* ws = (char*)d_ws;
  const size_t MB = 1024 * 1024;
  ushort_t* Xk  = (ushort_t*)(ws + 0 * MB);    // key   bf16 [4096][1024]
  ushort_t* Xq  = (ushort_t*)(ws + 8 * MB);    // query bf16
  ushort_t* Xv  = (ushort_t*)(ws + 16 * MB);   // value bf16
  ushort_t* Wqb = (ushort_t*)(ws + 24 * MB);   // pre-scaled by 0.125*log2e
  ushort_t* Wkb = (ushort_t*)(ws + 26 * MB);
  ushort_t* Wvb = (ushort_t*)(ws + 28 * MB);
  ushort_t* Wob = (ushort_t*)(ws + 30 * MB);
  ushort_t* Qp  = (ushort_t*)(ws + 32 * MB);   // projected Q (log2e-scaled)
  ushort_t* Kp  = (ushort_t*)(ws + 40 * MB);
  ushort_t* VpT = (ushort_t*)(ws + 48 * MB);   // [b][h][64][2048]
  ushort_t* Ob  = (ushort_t*)(ws + 56 * MB);   // attention out bf16

  CvtArgs ca;
  const size_t CE = 1048576;
  for (int c = 0; c < 16; ++c) ca.scale[c] = 1.0f;
  for (int c = 0; c < 4; ++c) { ca.src[c]     = key   + c * CE; ca.dst[c]     = Xk + c * CE; }
  for (int c = 0; c < 4; ++c) { ca.src[4 + c] = query + c * CE; ca.dst[4 + c] = Xq + c * CE; }
  for (int c = 0; c < 4; ++c) { ca.src[8 + c] = value + c * CE; ca.dst[8 + c] = Xv + c * CE; }
  ca.src[12] = Wq; ca.dst[12] = Wqb; ca.scale[12] = QK_SCALE;
  ca.src[13] = Wk; ca.dst[13] = Wkb;
  ca.src[14] = Wv; ca.dst[14] = Wvb;
  ca.src[15] = Wo; ca.dst[15] = Wob;
  cvt_kernel<<<8192, 256, 0, stream>>>(ca);

  QkvArgs qa;
  qa.A[0] = Xq; qa.W[0] = Wqb; qa.C[0] = (char*)Qp;
  qa.A[1] = Xk; qa.W[1] = Wkb; qa.C[1] = (char*)Kp;
  qa.A[2] = Xv; qa.W[2] = Wvb; qa.C[2] = (char*)VpT;   // z=2 writes transposed
  qkv_gemm<<<dim3(16, 16, 3), 512, 0, stream>>>(qa);

  attn_kernel<<<1024, 256, 0, stream>>>(Qp, Kp, VpT, Ob);

  o_gemm<<<dim3(32, 16), 256, 0, stream>>>(Ob, Wob, (float*)d_out);
}

// Round 11
// 241.820 us; speedup vs baseline: 2.6625x; 1.0660x over previous
//
#include <hip/hip_runtime.h>
#include <stdint.h>

// ---------------------------------------------------------------------------
// MHA block, round 17.
// r16 post-mortem: qkv BN=64 REGRESSED 57->87us (4th failed qkv experiment).
// Load volume through L2/L3 nearly doubled (A re-read 16x across y=16 sweep;
// FETCH flat at 37MB because L3 absorbs, but the fabric still moves ~490MB
// vs ~290MB) while MFMA-per-staging-step halved.  r7's qkv (55-59us measured
// three ways) is a volume-x-cache-BW-bound local optimum -> frozen.
// This round: restore r11-exact (238.8 best known) + ONE cheap lever:
//  * attn T5 s_setprio(1) around the QK^T and PV MFMA clusters.  attn runs
//    4 independent blocks/CU at different phases (not lockstep) -- the
//    regime where setprio measured +4-7% (m191).  Pure hint, zero risk.
// qkv = r7-exact 512-thr core; o_gemm = r10 BN=64; cvt unchanged.
// ---------------------------------------------------------------------------

typedef unsigned short ushort_t;
typedef __attribute__((ext_vector_type(8))) __bf16 bf16x8;   // MFMA A/B operand
typedef __attribute__((ext_vector_type(4))) float floatx4;   // MFMA C/D operand

#define EMBED 1024
#define SEQ   2048
#define NH    16
#define DH    64
#define QK_SCALE 0.18033688011112042f   // 0.125 * log2(e)

// fp32 -> bf16 round-to-nearest-even (finite inputs)
__device__ inline ushort_t f2b(float x) {
  unsigned u = __float_as_uint(x);
  u += 0x7FFFu + ((u >> 16) & 1u);
  return (ushort_t)(u >> 16);
}

// pack bf16(a) | bf16(b)<<16 with +0x8000 round: 2 add + 1 perm
__device__ inline unsigned pk2(float a, float b) {
  unsigned ua = __float_as_uint(a) + 0x8000u;
  unsigned ub = __float_as_uint(b) + 0x8000u;
  return __builtin_amdgcn_perm(ub, ua, 0x07060302u);   // [a2,a3,b2,b3]
}

// async global->LDS, 16B/lane; LDS dest = wave-uniform base (+ lane*16 by HW)
__device__ inline void gl_lds16(const ushort_t* g, ushort_t* l) {
  __builtin_amdgcn_global_load_lds(
      (const __attribute__((address_space(1))) unsigned int*)g,
      (__attribute__((address_space(3))) unsigned int*)l, 16, 0, 0);
}

// ---------------------------------------------------------------------------
// fp32 -> bf16 bulk convert, with per-chunk scale (folds QK scale into Wq)
// ---------------------------------------------------------------------------
struct CvtArgs {
  const float* src[16];
  ushort_t*    dst[16];
  float        scale[16];
};

__global__ __launch_bounds__(256) void cvt_kernel(CvtArgs a) {
  const int chunk = blockIdx.x >> 9;
  const int off = ((blockIdx.x & 511) << 11) + (threadIdx.x << 3);
  const float sc = a.scale[chunk];
  const float4* s = (const float4*)(a.src[chunk] + off);
  float4 f0 = s[0], f1 = s[1];
  union { ushort_t u[8]; uint4 v; } o;
  o.u[0] = f2b(f0.x * sc); o.u[1] = f2b(f0.y * sc);
  o.u[2] = f2b(f0.z * sc); o.u[3] = f2b(f0.w * sc);
  o.u[4] = f2b(f1.x * sc); o.u[5] = f2b(f1.y * sc);
  o.u[6] = f2b(f1.z * sc); o.u[7] = f2b(f1.w * sc);
  *(uint4*)(a.dst[chunk] + off) = o.v;
}

// ---------------------------------------------------------------------------
// Shared epilogue: write one 16x16 C subtile from C-layout accumulator.
//   mode 0 = bf16 row-major, 1 = f32 row-major, 2 = bf16 into VpT[b][h][d][s]
// ---------------------------------------------------------------------------
__device__ inline void store_sub(char* __restrict__ Cv, const int mode,
                                 const int ldc, const int row, const int col,
                                 const floatx4& acc) {
  if (mode == 0) {
    ushort_t* C = (ushort_t*)Cv;
#pragma unroll
    for (int r = 0; r < 4; ++r)
      C[(size_t)(row + r) * ldc + col] = f2b(acc[r]);
  } else if (mode == 1) {
    float* C = (float*)Cv;
#pragma unroll
    for (int r = 0; r < 4; ++r)
      C[(size_t)(row + r) * ldc + col] = acc[r];
  } else {
    // VpT[b][h][d][s]: r -> consecutive s, one 8B store
    ushort_t* C = (ushort_t*)Cv;
    const int b = row >> 11, s = row & 2047;
    const int h = col >> 6, d = col & 63;
    uint2 pk;
    pk.x = pk2(acc[0], acc[1]);
    pk.y = pk2(acc[2], acc[3]);
    *(uint2*)&C[(size_t)((b * NH + h) * DH + d) * SEQ + s] = pk;
  }
}

// ---------------------------------------------------------------------------
// 512-thread GEMM core (r7-exact): C[m,n] = sum_k A[m,k]*W[n,k], K=1024.
// BM=256, BN=128, BK=64; 8 waves as 4m x 2n, each wave 64x64 (4x4 subtiles).
// Single-buffer LDS 48KB, 2-barrier drain loop.  FROZEN: measured 55-59us
// three independent ways; 4 structural variants all regressed.
// ---------------------------------------------------------------------------
__device__ inline void gemm512_core(const ushort_t* __restrict__ A,
                                    const ushort_t* __restrict__ W,
                                    char* __restrict__ Cv, const int mode,
                                    const int ldc, const int m0, const int n0) {
  __shared__ ushort_t As[32 * 512];   // 256 x 64 bf16, fragment-ordered
  __shared__ ushort_t Bs[16 * 512];   // 128 x 64
  const int tid  = threadIdx.x;
  const int lane = tid & 63;
  const int wid  = tid >> 6;          // 0..7
  const int lm   = lane & 15;
  const int quad = lane >> 4;
  const int wm   = wid >> 1;          // 0..3
  const int wn   = wid & 1;           // 0..1

  floatx4 zero = {0.f, 0.f, 0.f, 0.f};
  floatx4 acc[4][4];
#pragma unroll
  for (int i = 0; i < 4; ++i)
#pragma unroll
    for (int j = 0; j < 4; ++j) acc[i][j] = zero;

  for (int k0 = 0; k0 < EMBED; k0 += 64) {
    __syncthreads();
#pragma unroll
    for (int u = 0; u < 6; ++u) {
      const int c   = wid * 6 + u;     // 0..47, wave-uniform
      const int cb  = c & 31;          // chunk within its array
      const int sub = cb >> 1;
      const int kc  = (cb & 1) * 32 + quad * 8;
      if (c < 32)
        gl_lds16(A + (size_t)(m0 + sub * 16 + lm) * EMBED + k0 + kc, &As[cb * 512]);
      else
        gl_lds16(W + (size_t)(n0 + sub * 16 + lm) * EMBED + k0 + kc, &Bs[cb * 512]);
    }
    __syncthreads();   // vmcnt drain -> LDS visible

#pragma unroll
    for (int ks = 0; ks < 2; ++ks) {
      bf16x8 a[4], b[4];
#pragma unroll
      for (int i = 0; i < 4; ++i)
        a[i] = *(const bf16x8*)&As[((wm * 4 + i) * 2 + ks) * 512 + lane * 8];
#pragma unroll
      for (int j = 0; j < 4; ++j)
        b[j] = *(const bf16x8*)&Bs[((wn * 4 + j) * 2 + ks) * 512 + lane * 8];
#pragma unroll
      for (int i = 0; i < 4; ++i)
#pragma unroll
        for (int j = 0; j < 4; ++j)
          acc[i][j] = __builtin_amdgcn_mfma_f32_16x16x32_bf16(a[i], b[j], acc[i][j], 0, 0, 0);
    }
  }

#pragma unroll
  for (int i = 0; i < 4; ++i) {
    const int row = m0 + wm * 64 + i * 16 + quad * 4;
#pragma unroll
    for (int j = 0; j < 4; ++j)
      store_sub(Cv, mode, ldc, row, n0 + wn * 64 + j * 16 + lm, acc[i][j]);
  }
}

struct QkvArgs {
  const ushort_t* A[3];
  const ushort_t* W[3];
  char*           C[3];
};

// grid (16,8,3) natural: blocks sharing an A-panel have bid%8 = x%8 fixed ->
// same XCD L2 across the y sweep (A-locality beats W-locality: 8MB vs 2MB).
__global__ __launch_bounds__(512, 4) void qkv_gemm(QkvArgs q) {
  const int z = blockIdx.z;
  gemm512_core(q.A[z], q.W[z], q.C[z], z == 2 ? 2 : 0, EMBED,
               blockIdx.x * 256, blockIdx.y * 128);
}

// ---------------------------------------------------------------------------
// O-projection GEMM (r10): BM=128, BN=64, BK=64, 256 thr (4 waves 2m x 2n,
// each wave 64x32 = 4x2 subtiles).  Grid (32,16) = 512 blocks = 2 blocks/CU,
// 8 waves/CU in 2 independent barrier domains.  LDS 24KB.
// ---------------------------------------------------------------------------
__global__ __launch_bounds__(256, 4) void o_gemm(const ushort_t* __restrict__ A,
                                                 const ushort_t* __restrict__ W,
                                                 float* __restrict__ C) {
  __shared__ ushort_t As[16 * 512];   // 128 x 64, fragment-ordered
  __shared__ ushort_t Bs[8 * 512];    // 64 x 64
  const int m0 = blockIdx.x * 128, n0 = blockIdx.y * 64;
  const int tid  = threadIdx.x;
  const int lane = tid & 63;
  const int wid  = tid >> 6;          // 0..3
  const int lm   = lane & 15;
  const int quad = lane >> 4;
  const int wm   = wid >> 1;          // 0..1
  const int wn   = wid & 1;           // 0..1

  floatx4 zero = {0.f, 0.f, 0.f, 0.f};
  floatx4 acc[4][2];
#pragma unroll
  for (int i = 0; i < 4; ++i)
#pragma unroll
    for (int j = 0; j < 2; ++j) acc[i][j] = zero;

  for (int k0 = 0; k0 < EMBED; k0 += 64) {
    __syncthreads();
#pragma unroll
    for (int u = 0; u < 6; ++u) {
      const int c   = wid * 6 + u;     // 0..23, wave-uniform
      const int cb  = (c < 16) ? c : (c - 16);
      const int sub = cb >> 1;
      const int kc  = (cb & 1) * 32 + quad * 8;
      if (c < 16)
        gl_lds16(A + (size_t)(m0 + sub * 16 + lm) * EMBED + k0 + kc, &As[cb * 512]);
      else
        gl_lds16(W + (size_t)(n0 + sub * 16 + lm) * EMBED + k0 + kc, &Bs[cb * 512]);
    }
    __syncthreads();   // vmcnt drain -> LDS visible

#pragma unroll
    for (int ks = 0; ks < 2; ++ks) {
      bf16x8 a[4], b[2];
#pragma unroll
      for (int i = 0; i < 4; ++i)
        a[i] = *(const bf16x8*)&As[((wm * 4 + i) * 2 + ks) * 512 + lane * 8];
#pragma unroll
      for (int j = 0; j < 2; ++j)
        b[j] = *(const bf16x8*)&Bs[((wn * 2 + j) * 2 + ks) * 512 + lane * 8];
#pragma unroll
      for (int i = 0; i < 4; ++i)
#pragma unroll
        for (int j = 0; j < 2; ++j)
          acc[i][j] = __builtin_amdgcn_mfma_f32_16x16x32_bf16(a[i], b[j], acc[i][j], 0, 0, 0);
    }
  }

#pragma unroll
  for (int i = 0; i < 4; ++i) {
    const int row = m0 + wm * 64 + i * 16 + quad * 4;
#pragma unroll
    for (int j = 0; j < 2; ++j) {
      const int col = n0 + wn * 32 + j * 16 + lm;
#pragma unroll
      for (int r = 0; r < 4; ++r)
        C[(size_t)(row + r) * EMBED + col] = acc[i][j][r];
    }
  }
}

// ---------------------------------------------------------------------------
// Causal flash attention, S^T formulation, fixed-shift softmax, K/V dbuf.
// Grid 1024 x 256thr (4 waves).  Block = 64 q-cols of one (b,h); wave owns
// 16 q.  KT=64.  One barrier per iter; next K/V tile's global_load_lds
// issued right after the barrier, landing during compute.
// LDS 40KB -> 4 blocks/CU (16 waves/CU, 4/SIMD from 4 independent blocks).
// qb map: slot s=(L>>5)&7, group g=L>>8: {s, 15-s, 16+s, 31-s} -> the 4
// blocks sharing a CU under round-robin dispatch sum to 66 iters, uniform.
// bh stays in L&31 -> bh%8 == L%8 pins each head's K/V to one XCD L2.
// r17: + s_setprio(1) around QK^T and PV MFMA clusters (T5; 4 independent
// blocks/CU at different phases = the regime where setprio pays, m191).
// ---------------------------------------------------------------------------
__global__ __launch_bounds__(256, 4) void attn_kernel(const ushort_t* __restrict__ Qp,
                                                      const ushort_t* __restrict__ Kp,
                                                      const ushort_t* __restrict__ VpT,
                                                      ushort_t* __restrict__ Ob) {
  __shared__ ushort_t Qs[8 * 512];       // 64 q x 64 d; aliased as P scratch
  __shared__ ushort_t Ks[2][8 * 512];    // dbuf: 64 kk x 64 d
  __shared__ ushort_t VTs[2][8 * 512];   // dbuf: 64 d x 64 kk
  const int L = blockIdx.x;              // 0..1023
  const int s8 = (L >> 5) & 7;
  const int g  = L >> 8;                 // 0..3
  const int qb = (g == 0) ? s8
               : (g == 1) ? (15 - s8)
               : (g == 2) ? (16 + s8)
                          : (31 - s8);
  const int bh = L & 31;
  const int h = bh & (NH - 1), b = bh >> 4;
  const int tid = threadIdx.x, lane = tid & 63, wid = tid >> 6;
  const int lm = lane & 15, quad = lane >> 4;
  const size_t qkbase = ((size_t)b * SEQ) * EMBED + h * DH;
  const size_t vtbase = ((size_t)(b * NH + h)) * DH * SEQ;

  // Q staging: 4 chunks of 512; wave's pair c = wid*2 + u covers its 16 q.
#pragma unroll
  for (int u = 0; u < 2; ++u) {
    const int c = wid * 2 + u;
    gl_lds16(Qp + qkbase + (size_t)(qb * 64 + (c >> 1) * 16 + lm) * EMBED
                 + (c & 1) * 32 + quad * 8,
             &Qs[c * 512]);
  }
  // issue K/V for kt=0 into buf 0 (behind the Q loads)
#pragma unroll
  for (int u = 0; u < 4; ++u) {
    const int t = wid * 4 + u;
    const int cb = t & 7, sub = cb >> 1, half = cb & 1;
    if (t < 8)
      gl_lds16(Kp + qkbase + (size_t)(sub * 16 + lm) * EMBED + half * 32 + quad * 8,
               &Ks[0][cb * 512]);
    else
      gl_lds16(VpT + vtbase + (size_t)(sub * 16 + lm) * SEQ + half * 32 + quad * 8,
               &VTs[0][cb * 512]);
  }
  asm volatile("s_waitcnt vmcnt(4)" ::: "memory");   // my Q chunks landed
  bf16x8 qf[2];   // [ks]
#pragma unroll
  for (int ks = 0; ks < 2; ++ks)
    qf[ks] = *(const bf16x8*)&Qs[(wid * 2 + ks) * 512 + lane * 8];
  // Q region is now dead; reuse the wave's own 2KB slice as P scratch.
  ushort_t* pwb = &Qs[wid * 1024];

  float l_part = 0.f;
  floatx4 zero = {0.f, 0.f, 0.f, 0.f};
  floatx4 o_acc[4];
#pragma unroll
  for (int d = 0; d < 4; ++d) o_acc[d] = zero;

  for (int kt = 0; kt <= qb; ++kt) {
    const int cur = kt & 1;
    // my K/V[cur] loads (issued last iter / preamble) have landed by now
    asm volatile("s_waitcnt vmcnt(0)" ::: "memory");
    __syncthreads();   // all waves' cur loads landed; all done reading buf cur^1
    if (kt < qb) {
      const int kn = kt + 1;
#pragma unroll
      for (int u = 0; u < 4; ++u) {
        const int t = wid * 4 + u;
        const int cb = t & 7, sub = cb >> 1, half = cb & 1;
        if (t < 8)
          gl_lds16(Kp + qkbase + (size_t)(kn * 64 + sub * 16 + lm) * EMBED
                       + half * 32 + quad * 8,
                   &Ks[cur ^ 1][cb * 512]);
        else
          gl_lds16(VpT + vtbase + (size_t)(sub * 16 + lm) * SEQ
                       + kn * 64 + half * 32 + quad * 8,
                   &VTs[cur ^ 1][cb * 512]);
      }
    }

    // S^T = K Q^T (log2e domain): s_acc[i], i = kk-subtile 0..3
    floatx4 s_acc[4];
#pragma unroll
    for (int i = 0; i < 4; ++i) s_acc[i] = zero;
    __builtin_amdgcn_s_setprio(1);   // T5: favor this wave's MFMA cluster
#pragma unroll
    for (int ks = 0; ks < 2; ++ks)
#pragma unroll
      for (int i = 0; i < 4; ++i) {
        bf16x8 kf = *(const bf16x8*)&Ks[cur][(i * 2 + ks) * 512 + lane * 8];
        s_acc[i] = __builtin_amdgcn_mfma_f32_16x16x32_bf16(kf, qf[ks], s_acc[i], 0, 0, 0);
      }
    __builtin_amdgcn_s_setprio(0);

    // exp2, diagonal mask, l accumulate, pack P^T into wave-private scratch
    const bool diag = (kt == qb);   // uniform branch; last iter only
#pragma unroll
    for (int i = 0; i < 4; ++i) {
      const int sH = i >> 1;
      const int quadB = ((i & 1) << 1) | (quad >> 1);
      const int gkk = kt * 64 + i * 16 + quad * 4;
      float p[4];
#pragma unroll
      for (int r = 0; r < 4; ++r) p[r] = __builtin_amdgcn_exp2f(s_acc[i][r]);
      if (diag) {
        const int gq = qb * 64 + wid * 16 + lm;
#pragma unroll
        for (int r = 0; r < 4; ++r)
          if (gkk + r > gq) p[r] = 0.f;
      }
#pragma unroll
      for (int r = 0; r < 4; ++r) l_part += p[r];
      uint2 pk;
      pk.x = pk2(p[0], p[1]);
      pk.y = pk2(p[2], p[3]);
      *(uint2*)&pwb[sH * 512 + (quadB * 16 + lm) * 8 + ((quad & 1) << 2)] = pk;
    }
    asm volatile("s_waitcnt lgkmcnt(0)" ::: "memory");   // wave-local RAW fence

    // O^T += V^T P^T
    __builtin_amdgcn_s_setprio(1);   // T5
#pragma unroll
    for (int sH = 0; sH < 2; ++sH) {
      bf16x8 pf = *(const bf16x8*)&pwb[sH * 512 + lane * 8];
#pragma unroll
      for (int d = 0; d < 4; ++d) {
        bf16x8 vf = *(const bf16x8*)&VTs[cur][(d * 2 + sH) * 512 + lane * 8];
        o_acc[d] = __builtin_amdgcn_mfma_f32_16x16x32_bf16(vf, pf, o_acc[d], 0, 0, 0);
      }
    }
    __builtin_amdgcn_s_setprio(0);
  }

  // epilogue
  {
    float l = l_part;
    l += __shfl_xor(l, 16, 64);
    l += __shfl_xor(l, 32, 64);
    const float inv_l = 1.0f / l;
    const size_t orow = qkbase + (size_t)(qb * 64 + wid * 16 + lm) * EMBED;
#pragma unroll
    for (int d = 0; d < 4; ++d) {
      uint2 pk;
      pk.x = pk2(o_acc[d][0] * inv_l, o_acc[d][1] * inv_l);
      pk.y = pk2(o_acc[d][2] * inv_l, o_acc[d][3] * inv_l);
      *(uint2*)&Ob[orow + d * 16 + quad * 4] = pk;
    }
  }
}

// ---------------------------------------------------------------------------
// launch
// ---------------------------------------------------------------------------
extern "C" void kernel_launch(void* const* d_in, const int* in_sizes, int n_in,
                              void* d_out, int out_size, void* d_ws, size_t ws_size,
                              hipStream_t stream) {
  // setup_inputs() order: key, query, value, mask, Wq, Wk, Wv, Wo
  const float* key   = (const float*)d_in[0];
  const float* query = (const float*)d_in[1];
  const float* value = (const float*)d_in[2];
  // d_in[3] = static causal tril, handled analytically
  const float* Wq = (const float*)d_in[4];
  const float* Wk = (const float*)d_in[5];
  const float* Wv = (const float*)d_in[6];
  const float* Wo = (const float*)d_in[7];

  char* ws = (char*)d_ws;
  const size_t MB = 1024 * 1024;
  ushort_t* Xk  = (ushort_t*)(ws + 0 * MB);    // key   bf16 [4096][1024]
  ushort_t* Xq  = (ushort_t*)(ws + 8 * MB);    // query bf16
  ushort_t* Xv  = (ushort_t*)(ws + 16 * MB);   // value bf16
  ushort_t* Wqb = (ushort_t*)(ws + 24 * MB);   // pre-scaled by 0.125*log2e
  ushort_t* Wkb = (ushort_t*)(ws + 26 * MB);
  ushort_t* Wvb = (ushort_t*)(ws + 28 * MB);
  ushort_t* Wob = (ushort_t*)(ws + 30 * MB);
  ushort_t* Qp  = (ushort_t*)(ws + 32 * MB);   // projected Q (log2e-scaled)
  ushort_t* Kp  = (ushort_t*)(ws + 40 * MB);
  ushort_t* VpT = (ushort_t*)(ws + 48 * MB);   // [b][h][64][2048]
  ushort_t* Ob  = (ushort_t*)(ws + 56 * MB);   // attention out bf16

  CvtArgs ca;
  const size_t CE = 1048576;
  for (int c = 0; c < 16; ++c) ca.scale[c] = 1.0f;
  for (int c = 0; c < 4; ++c) { ca.src[c]     = key   + c * CE; ca.dst[c]     = Xk + c * CE; }
  for (int c = 0; c < 4; ++c) { ca.src[4 + c] = query + c * CE; ca.dst[4 + c] = Xq + c * CE; }
  for (int c = 0; c < 4; ++c) { ca.src[8 + c] = value + c * CE; ca.dst[8 + c] = Xv + c * CE; }
  ca.src[12] = Wq; ca.dst[12] = Wqb; ca.scale[12] = QK_SCALE;
  ca.src[13] = Wk; ca.dst[13] = Wkb;
  ca.src[14] = Wv; ca.dst[14] = Wvb;
  ca.src[15] = Wo; ca.dst[15] = Wob;
  cvt_kernel<<<8192, 256, 0, stream>>>(ca);

  QkvArgs qa;
  qa.A[0] = Xq; qa.W[0] = Wqb; qa.C[0] = (char*)Qp;
  qa.A[1] = Xk; qa.W[1] = Wkb; qa.C[1] = (char*)Kp;
  qa.A[2] = Xv; qa.W[2] = Wvb; qa.C[2] = (char*)VpT;   // z=2 writes transposed
  qkv_gemm<<<dim3(16, 8, 3), 512, 0, stream>>>(qa);

  attn_kernel<<<1024, 256, 0, stream>>>(Qp, Kp, VpT, Ob);

  o_gemm<<<dim3(32, 16), 256, 0, stream>>>(Ob, Wob, (float*)d_out);
}

// Round 12
// 230.502 us; speedup vs baseline: 2.7933x; 1.0491x over previous
//
#include <hip/hip_runtime.h>
#include <stdint.h>

// ---------------------------------------------------------------------------
// MHA block, round 18.
// r17 post-mortem: attn setprio ~neutral-negative (241.8 vs 238.8) -> dropped.
// qkv re-confirmed 55.5-57us / MfmaUtil 16.5 -- not a roofline.
// This round: port the VERIFIED 8-phase schedule (m194-m201 template) onto
// our conflict-free fragment-ordered LDS (measured 0 bank conflicts all
// session -> template's st_16x32 swizzle unnecessary; only the SCHEDULE is
// ported).  My 4 failed qkv variants all kept the coarse bulk-stage loop;
// m196/m218 say the fine per-phase interleave + counted vmcnt IS the lever.
//  * 256x256 tile, BK=64, 512thr (8 waves 2Mx4N, wave=128x64, acc[8][4]).
//  * LDS 128KB: As[2]/Bs[2] 32KB each; K-half == phase ks -> half-tile
//    (32KB) consumed by exactly 2 phases.
//  * 4 phases/K-step: {ds_read frags || 2 gl_lds prefetch -> s_barrier ->
//    setprio(1) 16 MFMA setprio(0) -> s_barrier}.
//  * counted vmcnt(4) ONLY before trailing barrier of phases 1 & 3 (4 loads
//    always in flight across barriers; ~2-3 MFMA phases latency cover);
//    vmcnt(0) at t=15 tail.  Prologue: stage tile0, vmcnt(4), barrier.
//  * grid (16,4,3) = 192 blocks, 1 round; z-major keeps A-panel sharers
//    on one XCD.
// cvt/attn/o_gemm r11-exact (attn setprio removed).
// ---------------------------------------------------------------------------

typedef unsigned short ushort_t;
typedef __attribute__((ext_vector_type(8))) __bf16 bf16x8;   // MFMA A/B operand
typedef __attribute__((ext_vector_type(4))) float floatx4;   // MFMA C/D operand

#define EMBED 1024
#define SEQ   2048
#define NH    16
#define DH    64
#define QK_SCALE 0.18033688011112042f   // 0.125 * log2(e)

// fp32 -> bf16 round-to-nearest-even (finite inputs)
__device__ inline ushort_t f2b(float x) {
  unsigned u = __float_as_uint(x);
  u += 0x7FFFu + ((u >> 16) & 1u);
  return (ushort_t)(u >> 16);
}

// pack bf16(a) | bf16(b)<<16 with +0x8000 round: 2 add + 1 perm
__device__ inline unsigned pk2(float a, float b) {
  unsigned ua = __float_as_uint(a) + 0x8000u;
  unsigned ub = __float_as_uint(b) + 0x8000u;
  return __builtin_amdgcn_perm(ub, ua, 0x07060302u);   // [a2,a3,b2,b3]
}

// async global->LDS, 16B/lane; LDS dest = wave-uniform base (+ lane*16 by HW)
__device__ inline void gl_lds16(const ushort_t* g, ushort_t* l) {
  __builtin_amdgcn_global_load_lds(
      (const __attribute__((address_space(1))) unsigned int*)g,
      (__attribute__((address_space(3))) unsigned int*)l, 16, 0, 0);
}

// ---------------------------------------------------------------------------
// fp32 -> bf16 bulk convert, with per-chunk scale (folds QK scale into Wq)
// ---------------------------------------------------------------------------
struct CvtArgs {
  const float* src[16];
  ushort_t*    dst[16];
  float        scale[16];
};

__global__ __launch_bounds__(256) void cvt_kernel(CvtArgs a) {
  const int chunk = blockIdx.x >> 9;
  const int off = ((blockIdx.x & 511) << 11) + (threadIdx.x << 3);
  const float sc = a.scale[chunk];
  const float4* s = (const float4*)(a.src[chunk] + off);
  float4 f0 = s[0], f1 = s[1];
  union { ushort_t u[8]; uint4 v; } o;
  o.u[0] = f2b(f0.x * sc); o.u[1] = f2b(f0.y * sc);
  o.u[2] = f2b(f0.z * sc); o.u[3] = f2b(f0.w * sc);
  o.u[4] = f2b(f1.x * sc); o.u[5] = f2b(f1.y * sc);
  o.u[6] = f2b(f1.z * sc); o.u[7] = f2b(f1.w * sc);
  *(uint4*)(a.dst[chunk] + off) = o.v;
}

// ---------------------------------------------------------------------------
// Shared epilogue: write one 16x16 C subtile from C-layout accumulator.
//   mode 0 = bf16 row-major, 1 = f32 row-major, 2 = bf16 into VpT[b][h][d][s]
// ---------------------------------------------------------------------------
__device__ inline void store_sub(char* __restrict__ Cv, const int mode,
                                 const int ldc, const int row, const int col,
                                 const floatx4& acc) {
  if (mode == 0) {
    ushort_t* C = (ushort_t*)Cv;
#pragma unroll
    for (int r = 0; r < 4; ++r)
      C[(size_t)(row + r) * ldc + col] = f2b(acc[r]);
  } else if (mode == 1) {
    float* C = (float*)Cv;
#pragma unroll
    for (int r = 0; r < 4; ++r)
      C[(size_t)(row + r) * ldc + col] = acc[r];
  } else {
    // VpT[b][h][d][s]: r -> consecutive s, one 8B store
    ushort_t* C = (ushort_t*)Cv;
    const int b = row >> 11, s = row & 2047;
    const int h = col >> 6, d = col & 63;
    uint2 pk;
    pk.x = pk2(acc[0], acc[1]);
    pk.y = pk2(acc[2], acc[3]);
    *(uint2*)&C[(size_t)((b * NH + h) * DH + d) * SEQ + s] = pk;
  }
}

// ---------------------------------------------------------------------------
// 8-phase 512-thread GEMM core: C[m,n] = sum_k A[m,k]*W[n,k], K=1024 fixed.
// BM=BN=256, BK=64.  8 waves as 2M x 4N; wave owns 128x64 (8x4 subtiles).
// Fragment-ordered LDS chunks (1KB each; lane reads linear 16B -> 0 bank
// conflicts): A chunk (sub*2+ks) holds rows sub*16..+15, K-half ks.
// Staging: wave wid owns chunks wid*8+ul, ul 0..7; ul parity == K-half.
// Per K-step, 4 phases (ks, m-half); phase issues 2 gl_lds of the NEXT
// tile (pairs: ul{0,2},{4,6},{1,3},{5,7} -> halves 0,0,1,1), reads its
// frag chunks, barriers, 16 MFMA under setprio.  vmcnt(4) before the
// trailing barrier of phases 1 & 3 keeps 4 loads in flight ACROSS barriers.
// ---------------------------------------------------------------------------
__device__ inline void stage_pair(const ushort_t* __restrict__ A,
                                  const ushort_t* __restrict__ W,
                                  const int m0, const int n0, const int k0,
                                  ushort_t* __restrict__ Asb,
                                  ushort_t* __restrict__ Bsb,
                                  const int wid, const int lm, const int quad,
                                  const int pair) {
#pragma unroll
  for (int e = 0; e < 2; ++e) {
    const int ul = (pair < 2) ? (pair * 4 + e * 2)          // 0,2 / 4,6  (half0)
                              : ((pair - 2) * 4 + e * 2 + 1); // 1,3 / 5,7  (half1)
    const int c  = wid * 8 + ul;       // 0..63; <32 = A chunks, else B
    const int cb = c & 31;
    const int sub = cb >> 1;
    const int kc  = (cb & 1) * 32 + quad * 8;
    if (c < 32)
      gl_lds16(A + (size_t)(m0 + sub * 16 + lm) * EMBED + k0 + kc, &Asb[cb * 512]);
    else
      gl_lds16(W + (size_t)(n0 + sub * 16 + lm) * EMBED + k0 + kc, &Bsb[cb * 512]);
  }
}

__device__ inline void gemm512_8ph(const ushort_t* __restrict__ A,
                                   const ushort_t* __restrict__ W,
                                   char* __restrict__ Cv, const int mode,
                                   const int ldc, const int m0, const int n0) {
  __shared__ ushort_t As[2][32 * 512];   // 2 x 32KB
  __shared__ ushort_t Bs[2][32 * 512];   // 2 x 32KB
  const int tid  = threadIdx.x;
  const int lane = tid & 63;
  const int wid  = tid >> 6;          // 0..7
  const int lm   = lane & 15;
  const int quad = lane >> 4;
  const int wm2  = wid >> 2;          // 0..1  (M half: 128 rows)
  const int wn4  = wid & 3;           // 0..3  (N quarter: 64 cols)

  floatx4 zero = {0.f, 0.f, 0.f, 0.f};
  floatx4 acc[8][4];
#pragma unroll
  for (int i = 0; i < 8; ++i)
#pragma unroll
    for (int j = 0; j < 4; ++j) acc[i][j] = zero;

  // prologue: stage tile 0 (halves in order), wait half0, barrier
#pragma unroll
  for (int p = 0; p < 4; ++p)
    stage_pair(A, W, m0, n0, 0, As[0], Bs[0], wid, lm, quad, p);
  asm volatile("s_waitcnt vmcnt(4)" ::: "memory");
  asm volatile("s_barrier" ::: "memory");

#pragma unroll 1
  for (int t = 0; t < 16; ++t) {
    const int cur = t & 1;
    ushort_t* Ac = As[cur];
    ushort_t* Bc = Bs[cur];
    ushort_t* An = As[cur ^ 1];
    ushort_t* Bn = Bs[cur ^ 1];
    const int kn = (t + 1) << 6;
    const bool pf = (t < 15);

    bf16x8 a[4], b[4];

    // ---- phase 0: ks=0, mh=0 ----
#pragma unroll
    for (int i = 0; i < 4; ++i)
      a[i] = *(const bf16x8*)&Ac[((wm2 * 8 + i) * 2 + 0) * 512 + lane * 8];
#pragma unroll
    for (int j = 0; j < 4; ++j)
      b[j] = *(const bf16x8*)&Bc[((wn4 * 4 + j) * 2 + 0) * 512 + lane * 8];
    if (pf) stage_pair(A, W, m0, n0, kn, An, Bn, wid, lm, quad, 0);
    asm volatile("s_barrier" ::: "memory");
    __builtin_amdgcn_s_setprio(1);
#pragma unroll
    for (int i = 0; i < 4; ++i)
#pragma unroll
      for (int j = 0; j < 4; ++j)
        acc[i][j] = __builtin_amdgcn_mfma_f32_16x16x32_bf16(a[i], b[j], acc[i][j], 0, 0, 0);
    __builtin_amdgcn_s_setprio(0);
    asm volatile("s_barrier" ::: "memory");

    // ---- phase 1: ks=0, mh=1 (reuse b) ----
#pragma unroll
    for (int i = 0; i < 4; ++i)
      a[i] = *(const bf16x8*)&Ac[((wm2 * 8 + 4 + i) * 2 + 0) * 512 + lane * 8];
    if (pf) stage_pair(A, W, m0, n0, kn, An, Bn, wid, lm, quad, 1);
    asm volatile("s_barrier" ::: "memory");
    __builtin_amdgcn_s_setprio(1);
#pragma unroll
    for (int i = 0; i < 4; ++i)
#pragma unroll
      for (int j = 0; j < 4; ++j)
        acc[4 + i][j] = __builtin_amdgcn_mfma_f32_16x16x32_bf16(a[i], b[j], acc[4 + i][j], 0, 0, 0);
    __builtin_amdgcn_s_setprio(0);
    // guard cur.half1 for phases 2-3 (my oldest 4 = cur.half1's loads)
    if (pf) asm volatile("s_waitcnt vmcnt(4)" ::: "memory");
    else    asm volatile("s_waitcnt vmcnt(0)" ::: "memory");
    asm volatile("s_barrier" ::: "memory");

    // ---- phase 2: ks=1, mh=0 ----
#pragma unroll
    for (int i = 0; i < 4; ++i)
      a[i] = *(const bf16x8*)&Ac[((wm2 * 8 + i) * 2 + 1) * 512 + lane * 8];
#pragma unroll
    for (int j = 0; j < 4; ++j)
      b[j] = *(const bf16x8*)&Bc[((wn4 * 4 + j) * 2 + 1) * 512 + lane * 8];
    if (pf) stage_pair(A, W, m0, n0, kn, An, Bn, wid, lm, quad, 2);
    asm volatile("s_barrier" ::: "memory");
    __builtin_amdgcn_s_setprio(1);
#pragma unroll
    for (int i = 0; i < 4; ++i)
#pragma unroll
      for (int j = 0; j < 4; ++j)
        acc[i][j] = __builtin_amdgcn_mfma_f32_16x16x32_bf16(a[i], b[j], acc[i][j], 0, 0, 0);
    __builtin_amdgcn_s_setprio(0);
    asm volatile("s_barrier" ::: "memory");

    // ---- phase 3: ks=1, mh=1 (reuse b) ----
#pragma unroll
    for (int i = 0; i < 4; ++i)
      a[i] = *(const bf16x8*)&Ac[((wm2 * 8 + 4 + i) * 2 + 1) * 512 + lane * 8];
    if (pf) stage_pair(A, W, m0, n0, kn, An, Bn, wid, lm, quad, 3);
    asm volatile("s_barrier" ::: "memory");
    __builtin_amdgcn_s_setprio(1);
#pragma unroll
    for (int i = 0; i < 4; ++i)
#pragma unroll
      for (int j = 0; j < 4; ++j)
        acc[4 + i][j] = __builtin_amdgcn_mfma_f32_16x16x32_bf16(a[i], b[j], acc[4 + i][j], 0, 0, 0);
    __builtin_amdgcn_s_setprio(0);
    // guard next.half0 for next step's phases 0-1
    if (pf) asm volatile("s_waitcnt vmcnt(4)" ::: "memory");
    asm volatile("s_barrier" ::: "memory");
  }

#pragma unroll
  for (int i = 0; i < 8; ++i) {
    const int row = m0 + wm2 * 128 + i * 16 + quad * 4;
#pragma unroll
    for (int j = 0; j < 4; ++j)
      store_sub(Cv, mode, ldc, row, n0 + wn4 * 64 + j * 16 + lm, acc[i][j]);
  }
}

struct QkvArgs {
  const ushort_t* A[3];
  const ushort_t* W[3];
  char*           C[3];
};

// grid (16,4,3) = 192 blocks, single round on 256 CUs.
__global__ __launch_bounds__(512, 2) void qkv_gemm(QkvArgs q) {
  const int z = blockIdx.z;
  gemm512_8ph(q.A[z], q.W[z], q.C[z], z == 2 ? 2 : 0, EMBED,
              blockIdx.x * 256, blockIdx.y * 256);
}

// ---------------------------------------------------------------------------
// O-projection GEMM (r10): BM=128, BN=64, BK=64, 256 thr (4 waves 2m x 2n,
// each wave 64x32 = 4x2 subtiles).  Grid (32,16) = 512 blocks = 2 blocks/CU,
// 8 waves/CU in 2 independent barrier domains.  LDS 24KB.
// ---------------------------------------------------------------------------
__global__ __launch_bounds__(256, 4) void o_gemm(const ushort_t* __restrict__ A,
                                                 const ushort_t* __restrict__ W,
                                                 float* __restrict__ C) {
  __shared__ ushort_t As[16 * 512];   // 128 x 64, fragment-ordered
  __shared__ ushort_t Bs[8 * 512];    // 64 x 64
  const int m0 = blockIdx.x * 128, n0 = blockIdx.y * 64;
  const int tid  = threadIdx.x;
  const int lane = tid & 63;
  const int wid  = tid >> 6;          // 0..3
  const int lm   = lane & 15;
  const int quad = lane >> 4;
  const int wm   = wid >> 1;          // 0..1
  const int wn   = wid & 1;           // 0..1

  floatx4 zero = {0.f, 0.f, 0.f, 0.f};
  floatx4 acc[4][2];
#pragma unroll
  for (int i = 0; i < 4; ++i)
#pragma unroll
    for (int j = 0; j < 2; ++j) acc[i][j] = zero;

  for (int k0 = 0; k0 < EMBED; k0 += 64) {
    __syncthreads();
#pragma unroll
    for (int u = 0; u < 6; ++u) {
      const int c   = wid * 6 + u;     // 0..23, wave-uniform
      const int cb  = (c < 16) ? c : (c - 16);
      const int sub = cb >> 1;
      const int kc  = (cb & 1) * 32 + quad * 8;
      if (c < 16)
        gl_lds16(A + (size_t)(m0 + sub * 16 + lm) * EMBED + k0 + kc, &As[cb * 512]);
      else
        gl_lds16(W + (size_t)(n0 + sub * 16 + lm) * EMBED + k0 + kc, &Bs[cb * 512]);
    }
    __syncthreads();   // vmcnt drain -> LDS visible

#pragma unroll
    for (int ks = 0; ks < 2; ++ks) {
      bf16x8 a[4], b[2];
#pragma unroll
      for (int i = 0; i < 4; ++i)
        a[i] = *(const bf16x8*)&As[((wm * 4 + i) * 2 + ks) * 512 + lane * 8];
#pragma unroll
      for (int j = 0; j < 2; ++j)
        b[j] = *(const bf16x8*)&Bs[((wn * 2 + j) * 2 + ks) * 512 + lane * 8];
#pragma unroll
      for (int i = 0; i < 4; ++i)
#pragma unroll
        for (int j = 0; j < 2; ++j)
          acc[i][j] = __builtin_amdgcn_mfma_f32_16x16x32_bf16(a[i], b[j], acc[i][j], 0, 0, 0);
    }
  }

#pragma unroll
  for (int i = 0; i < 4; ++i) {
    const int row = m0 + wm * 64 + i * 16 + quad * 4;
#pragma unroll
    for (int j = 0; j < 2; ++j) {
      const int col = n0 + wn * 32 + j * 16 + lm;
#pragma unroll
      for (int r = 0; r < 4; ++r)
        C[(size_t)(row + r) * EMBED + col] = acc[i][j][r];
    }
  }
}

// ---------------------------------------------------------------------------
// Causal flash attention, S^T formulation, fixed-shift softmax, K/V dbuf.
// Grid 1024 x 256thr (4 waves).  Block = 64 q-cols of one (b,h); wave owns
// 16 q.  KT=64.  One barrier per iter; next K/V tile's global_load_lds
// issued right after the barrier, landing during compute.
// LDS 40KB -> 4 blocks/CU (16 waves/CU, 4/SIMD from 4 independent blocks).
// qb map: slot s=(L>>5)&7, group g=L>>8: {s, 15-s, 16+s, 31-s} -> the 4
// blocks sharing a CU under round-robin dispatch sum to 66 iters, uniform.
// bh stays in L&31 -> bh%8 == L%8 pins each head's K/V to one XCD L2.
// (r11-exact; r17's setprio removed -- measured neutral-negative.)
// ---------------------------------------------------------------------------
__global__ __launch_bounds__(256, 4) void attn_kernel(const ushort_t* __restrict__ Qp,
                                                      const ushort_t* __restrict__ Kp,
                                                      const ushort_t* __restrict__ VpT,
                                                      ushort_t* __restrict__ Ob) {
  __shared__ ushort_t Qs[8 * 512];       // 64 q x 64 d; aliased as P scratch
  __shared__ ushort_t Ks[2][8 * 512];    // dbuf: 64 kk x 64 d
  __shared__ ushort_t VTs[2][8 * 512];   // dbuf: 64 d x 64 kk
  const int L = blockIdx.x;              // 0..1023
  const int s8 = (L >> 5) & 7;
  const int g  = L >> 8;                 // 0..3
  const int qb = (g == 0) ? s8
               : (g == 1) ? (15 - s8)
               : (g == 2) ? (16 + s8)
                          : (31 - s8);
  const int bh = L & 31;
  const int h = bh & (NH - 1), b = bh >> 4;
  const int tid = threadIdx.x, lane = tid & 63, wid = tid >> 6;
  const int lm = lane & 15, quad = lane >> 4;
  const size_t qkbase = ((size_t)b * SEQ) * EMBED + h * DH;
  const size_t vtbase = ((size_t)(b * NH + h)) * DH * SEQ;

  // Q staging: 4 chunks of 512; wave's pair c = wid*2 + u covers its 16 q.
#pragma unroll
  for (int u = 0; u < 2; ++u) {
    const int c = wid * 2 + u;
    gl_lds16(Qp + qkbase + (size_t)(qb * 64 + (c >> 1) * 16 + lm) * EMBED
                 + (c & 1) * 32 + quad * 8,
             &Qs[c * 512]);
  }
  // issue K/V for kt=0 into buf 0 (behind the Q loads)
#pragma unroll
  for (int u = 0; u < 4; ++u) {
    const int t = wid * 4 + u;
    const int cb = t & 7, sub = cb >> 1, half = cb & 1;
    if (t < 8)
      gl_lds16(Kp + qkbase + (size_t)(sub * 16 + lm) * EMBED + half * 32 + quad * 8,
               &Ks[0][cb * 512]);
    else
      gl_lds16(VpT + vtbase + (size_t)(sub * 16 + lm) * SEQ + half * 32 + quad * 8,
               &VTs[0][cb * 512]);
  }
  asm volatile("s_waitcnt vmcnt(4)" ::: "memory");   // my Q chunks landed
  bf16x8 qf[2];   // [ks]
#pragma unroll
  for (int ks = 0; ks < 2; ++ks)
    qf[ks] = *(const bf16x8*)&Qs[(wid * 2 + ks) * 512 + lane * 8];
  // Q region is now dead; reuse the wave's own 2KB slice as P scratch.
  ushort_t* pwb = &Qs[wid * 1024];

  float l_part = 0.f;
  floatx4 zero = {0.f, 0.f, 0.f, 0.f};
  floatx4 o_acc[4];
#pragma unroll
  for (int d = 0; d < 4; ++d) o_acc[d] = zero;

  for (int kt = 0; kt <= qb; ++kt) {
    const int cur = kt & 1;
    // my K/V[cur] loads (issued last iter / preamble) have landed by now
    asm volatile("s_waitcnt vmcnt(0)" ::: "memory");
    __syncthreads();   // all waves' cur loads landed; all done reading buf cur^1
    if (kt < qb) {
      const int kn = kt + 1;
#pragma unroll
      for (int u = 0; u < 4; ++u) {
        const int t = wid * 4 + u;
        const int cb = t & 7, sub = cb >> 1, half = cb & 1;
        if (t < 8)
          gl_lds16(Kp + qkbase + (size_t)(kn * 64 + sub * 16 + lm) * EMBED
                       + half * 32 + quad * 8,
                   &Ks[cur ^ 1][cb * 512]);
        else
          gl_lds16(VpT + vtbase + (size_t)(sub * 16 + lm) * SEQ
                       + kn * 64 + half * 32 + quad * 8,
                   &VTs[cur ^ 1][cb * 512]);
      }
    }

    // S^T = K Q^T (log2e domain): s_acc[i], i = kk-subtile 0..3
    floatx4 s_acc[4];
#pragma unroll
    for (int i = 0; i < 4; ++i) s_acc[i] = zero;
#pragma unroll
    for (int ks = 0; ks < 2; ++ks)
#pragma unroll
      for (int i = 0; i < 4; ++i) {
        bf16x8 kf = *(const bf16x8*)&Ks[cur][(i * 2 + ks) * 512 + lane * 8];
        s_acc[i] = __builtin_amdgcn_mfma_f32_16x16x32_bf16(kf, qf[ks], s_acc[i], 0, 0, 0);
      }

    // exp2, diagonal mask, l accumulate, pack P^T into wave-private scratch
    const bool diag = (kt == qb);   // uniform branch; last iter only
#pragma unroll
    for (int i = 0; i < 4; ++i) {
      const int sH = i >> 1;
      const int quadB = ((i & 1) << 1) | (quad >> 1);
      const int gkk = kt * 64 + i * 16 + quad * 4;
      float p[4];
#pragma unroll
      for (int r = 0; r < 4; ++r) p[r] = __builtin_amdgcn_exp2f(s_acc[i][r]);
      if (diag) {
        const int gq = qb * 64 + wid * 16 + lm;
#pragma unroll
        for (int r = 0; r < 4; ++r)
          if (gkk + r > gq) p[r] = 0.f;
      }
#pragma unroll
      for (int r = 0; r < 4; ++r) l_part += p[r];
      uint2 pk;
      pk.x = pk2(p[0], p[1]);
      pk.y = pk2(p[2], p[3]);
      *(uint2*)&pwb[sH * 512 + (quadB * 16 + lm) * 8 + ((quad & 1) << 2)] = pk;
    }
    asm volatile("s_waitcnt lgkmcnt(0)" ::: "memory");   // wave-local RAW fence

    // O^T += V^T P^T
#pragma unroll
    for (int sH = 0; sH < 2; ++sH) {
      bf16x8 pf = *(const bf16x8*)&pwb[sH * 512 + lane * 8];
#pragma unroll
      for (int d = 0; d < 4; ++d) {
        bf16x8 vf = *(const bf16x8*)&VTs[cur][(d * 2 + sH) * 512 + lane * 8];
        o_acc[d] = __builtin_amdgcn_mfma_f32_16x16x32_bf16(vf, pf, o_acc[d], 0, 0, 0);
      }
    }
  }

  // epilogue
  {
    float l = l_part;
    l += __shfl_xor(l, 16, 64);
    l += __shfl_xor(l, 32, 64);
    const float inv_l = 1.0f / l;
    const size_t orow = qkbase + (size_t)(qb * 64 + wid * 16 + lm) * EMBED;
#pragma unroll
    for (int d = 0; d < 4; ++d) {
      uint2 pk;
      pk.x = pk2(o_acc[d][0] * inv_l, o_acc[d][1] * inv_l);
      pk.y = pk2(o_acc[d][2] * inv_l, o_acc[d][3] * inv_l);
      *(uint2*)&Ob[orow + d * 16 + quad * 4] = pk;
    }
  }
}

// ---------------------------------------------------------------------------
// launch
// ---------------------------------------------------------------------------
extern "C" void kernel_launch(void* const* d_in, const int* in_sizes, int n_in,
                              void* d_out, int out_size, void* d_ws, size_t ws_size,
                              hipStream_t stream) {
  // setup_inputs() order: key, query, value, mask, Wq, Wk, Wv, Wo
  const float* key   = (const float*)d_in[0];
  const float* query = (const float*)d_in[1];
  const float* value = (const float*)d_in[2];
  // d_in[3] = static causal tril, handled analytically
  const float* Wq = (const float*)d_in[4];
  const float* Wk = (const float*)d_in[5];
  const float* Wv = (const float*)d_in[6];
  const float* Wo = (const float*)d_in[7];

  char* ws = (char*)d_ws;
  const size_t MB = 1024 * 1024;
  ushort_t* Xk  = (ushort_t*)(ws + 0 * MB);    // key   bf16 [4096][1024]
  ushort_t* Xq  = (ushort_t*)(ws + 8 * MB);    // query bf16
  ushort_t* Xv  = (ushort_t*)(ws + 16 * MB);   // value bf16
  ushort_t* Wqb = (ushort_t*)(ws + 24 * MB);   // pre-scaled by 0.125*log2e
  ushort_t* Wkb = (ushort_t*)(ws + 26 * MB);
  ushort_t* Wvb = (ushort_t*)(ws + 28 * MB);
  ushort_t* Wob = (ushort_t*)(ws + 30 * MB);
  ushort_t* Qp  = (ushort_t*)(ws + 32 * MB);   // projected Q (log2e-scaled)
  ushort_t* Kp  = (ushort_t*)(ws + 40 * MB);
  ushort_t* VpT = (ushort_t*)(ws + 48 * MB);   // [b][h][64][2048]
  ushort_t* Ob  = (ushort_t*)(ws + 56 * MB);   // attention out bf16

  CvtArgs ca;
  const size_t CE = 1048576;
  for (int c = 0; c < 16; ++c) ca.scale[c] = 1.0f;
  for (int c = 0; c < 4; ++c) { ca.src[c]     = key   + c * CE; ca.dst[c]     = Xk + c * CE; }
  for (int c = 0; c < 4; ++c) { ca.src[4 + c] = query + c * CE; ca.dst[4 + c] = Xq + c * CE; }
  for (int c = 0; c < 4; ++c) { ca.src[8 + c] = value + c * CE; ca.dst[8 + c] = Xv + c * CE; }
  ca.src[12] = Wq; ca.dst[12] = Wqb; ca.scale[12] = QK_SCALE;
  ca.src[13] = Wk; ca.dst[13] = Wkb;
  ca.src[14] = Wv; ca.dst[14] = Wvb;
  ca.src[15] = Wo; ca.dst[15] = Wob;
  cvt_kernel<<<8192, 256, 0, stream>>>(ca);

  QkvArgs qa;
  qa.A[0] = Xq; qa.W[0] = Wqb; qa.C[0] = (char*)Qp;
  qa.A[1] = Xk; qa.W[1] = Wkb; qa.C[1] = (char*)Kp;
  qa.A[2] = Xv; qa.W[2] = Wvb; qa.C[2] = (char*)VpT;   // z=2 writes transposed
  qkv_gemm<<<dim3(16, 4, 3), 512, 0, stream>>>(qa);

  attn_kernel<<<1024, 256, 0, stream>>>(Qp, Kp, VpT, Ob);

  o_gemm<<<dim3(32, 16), 256, 0, stream>>>(Ob, Wob, (float*)d_out);
}

// Round 13
// 227.399 us; speedup vs baseline: 2.8314x; 1.0136x over previous
//
#include <hip/hip_runtime.h>
#include <stdint.h>

// ---------------------------------------------------------------------------
// MHA block, round 19.
// r18 post-mortem: 8-phase qkv WORKED -- qkv out of top-5 (<47.5us, was
// 55.5); total 230.5 best-of-session.  Fine interleave + counted vmcnt was
// the missing lever (m196/m218 transferred).  qkv frozen.
// New head: attn 47.5us, Occupancy 23.6% vs 50% design.  Cause: per-CU
// block set {s,15-s,16+s,31-s} has iters {1,16,17,32} -- sum uniform 66 but
// the 32-iter block runs ALONE after its companions retire (~iter 17);
// half the kernel lifetime is 1 block/CU = 4 waves (the latency-exposed
// regime).  Time-avg waves 66/33/4*16 ~= 8 -> 25%, matches counter.
// Change (one variable): pair long-with-long.  qb map ->
// {2s, 2s+1, 30-2s, 31-2s}: the two long blocks differ by 1 iter, tail
// runs 2 blocks (8 waves) to ~iter 30.  Sum still 66; bijective; bh=L&31
// unchanged (same-head L2 pinning + 4-blocks-share-head preserved).
// cvt/o_gemm r11-exact.
// ---------------------------------------------------------------------------

typedef unsigned short ushort_t;
typedef __attribute__((ext_vector_type(8))) __bf16 bf16x8;   // MFMA A/B operand
typedef __attribute__((ext_vector_type(4))) float floatx4;   // MFMA C/D operand

#define EMBED 1024
#define SEQ   2048
#define NH    16
#define DH    64
#define QK_SCALE 0.18033688011112042f   // 0.125 * log2(e)

// fp32 -> bf16 round-to-nearest-even (finite inputs)
__device__ inline ushort_t f2b(float x) {
  unsigned u = __float_as_uint(x);
  u += 0x7FFFu + ((u >> 16) & 1u);
  return (ushort_t)(u >> 16);
}

// pack bf16(a) | bf16(b)<<16 with +0x8000 round: 2 add + 1 perm
__device__ inline unsigned pk2(float a, float b) {
  unsigned ua = __float_as_uint(a) + 0x8000u;
  unsigned ub = __float_as_uint(b) + 0x8000u;
  return __builtin_amdgcn_perm(ub, ua, 0x07060302u);   // [a2,a3,b2,b3]
}

// async global->LDS, 16B/lane; LDS dest = wave-uniform base (+ lane*16 by HW)
__device__ inline void gl_lds16(const ushort_t* g, ushort_t* l) {
  __builtin_amdgcn_global_load_lds(
      (const __attribute__((address_space(1))) unsigned int*)g,
      (__attribute__((address_space(3))) unsigned int*)l, 16, 0, 0);
}

// ---------------------------------------------------------------------------
// fp32 -> bf16 bulk convert, with per-chunk scale (folds QK scale into Wq)
// ---------------------------------------------------------------------------
struct CvtArgs {
  const float* src[16];
  ushort_t*    dst[16];
  float        scale[16];
};

__global__ __launch_bounds__(256) void cvt_kernel(CvtArgs a) {
  const int chunk = blockIdx.x >> 9;
  const int off = ((blockIdx.x & 511) << 11) + (threadIdx.x << 3);
  const float sc = a.scale[chunk];
  const float4* s = (const float4*)(a.src[chunk] + off);
  float4 f0 = s[0], f1 = s[1];
  union { ushort_t u[8]; uint4 v; } o;
  o.u[0] = f2b(f0.x * sc); o.u[1] = f2b(f0.y * sc);
  o.u[2] = f2b(f0.z * sc); o.u[3] = f2b(f0.w * sc);
  o.u[4] = f2b(f1.x * sc); o.u[5] = f2b(f1.y * sc);
  o.u[6] = f2b(f1.z * sc); o.u[7] = f2b(f1.w * sc);
  *(uint4*)(a.dst[chunk] + off) = o.v;
}

// ---------------------------------------------------------------------------
// Shared epilogue: write one 16x16 C subtile from C-layout accumulator.
//   mode 0 = bf16 row-major, 1 = f32 row-major, 2 = bf16 into VpT[b][h][d][s]
// ---------------------------------------------------------------------------
__device__ inline void store_sub(char* __restrict__ Cv, const int mode,
                                 const int ldc, const int row, const int col,
                                 const floatx4& acc) {
  if (mode == 0) {
    ushort_t* C = (ushort_t*)Cv;
#pragma unroll
    for (int r = 0; r < 4; ++r)
      C[(size_t)(row + r) * ldc + col] = f2b(acc[r]);
  } else if (mode == 1) {
    float* C = (float*)Cv;
#pragma unroll
    for (int r = 0; r < 4; ++r)
      C[(size_t)(row + r) * ldc + col] = acc[r];
  } else {
    // VpT[b][h][d][s]: r -> consecutive s, one 8B store
    ushort_t* C = (ushort_t*)Cv;
    const int b = row >> 11, s = row & 2047;
    const int h = col >> 6, d = col & 63;
    uint2 pk;
    pk.x = pk2(acc[0], acc[1]);
    pk.y = pk2(acc[2], acc[3]);
    *(uint2*)&C[(size_t)((b * NH + h) * DH + d) * SEQ + s] = pk;
  }
}

// ---------------------------------------------------------------------------
// 8-phase 512-thread GEMM core: C[m,n] = sum_k A[m,k]*W[n,k], K=1024 fixed.
// BM=BN=256, BK=64.  8 waves as 2M x 4N; wave owns 128x64 (8x4 subtiles).
// Fragment-ordered LDS chunks (1KB each; lane reads linear 16B -> 0 bank
// conflicts).  Per K-step, 4 phases; phase issues 2 gl_lds of the NEXT
// tile, reads its frag chunks, barriers, 16 MFMA under setprio.  vmcnt(4)
// before the trailing barrier of phases 1 & 3 keeps 4 loads in flight
// across barriers.  (r18-verified: qkv <47.5us.)
// ---------------------------------------------------------------------------
__device__ inline void stage_pair(const ushort_t* __restrict__ A,
                                  const ushort_t* __restrict__ W,
                                  const int m0, const int n0, const int k0,
                                  ushort_t* __restrict__ Asb,
                                  ushort_t* __restrict__ Bsb,
                                  const int wid, const int lm, const int quad,
                                  const int pair) {
#pragma unroll
  for (int e = 0; e < 2; ++e) {
    const int ul = (pair < 2) ? (pair * 4 + e * 2)          // 0,2 / 4,6  (half0)
                              : ((pair - 2) * 4 + e * 2 + 1); // 1,3 / 5,7  (half1)
    const int c  = wid * 8 + ul;       // 0..63; <32 = A chunks, else B
    const int cb = c & 31;
    const int sub = cb >> 1;
    const int kc  = (cb & 1) * 32 + quad * 8;
    if (c < 32)
      gl_lds16(A + (size_t)(m0 + sub * 16 + lm) * EMBED + k0 + kc, &Asb[cb * 512]);
    else
      gl_lds16(W + (size_t)(n0 + sub * 16 + lm) * EMBED + k0 + kc, &Bsb[cb * 512]);
  }
}

__device__ inline void gemm512_8ph(const ushort_t* __restrict__ A,
                                   const ushort_t* __restrict__ W,
                                   char* __restrict__ Cv, const int mode,
                                   const int ldc, const int m0, const int n0) {
  __shared__ ushort_t As[2][32 * 512];   // 2 x 32KB
  __shared__ ushort_t Bs[2][32 * 512];   // 2 x 32KB
  const int tid  = threadIdx.x;
  const int lane = tid & 63;
  const int wid  = tid >> 6;          // 0..7
  const int lm   = lane & 15;
  const int quad = lane >> 4;
  const int wm2  = wid >> 2;          // 0..1  (M half: 128 rows)
  const int wn4  = wid & 3;           // 0..3  (N quarter: 64 cols)

  floatx4 zero = {0.f, 0.f, 0.f, 0.f};
  floatx4 acc[8][4];
#pragma unroll
  for (int i = 0; i < 8; ++i)
#pragma unroll
    for (int j = 0; j < 4; ++j) acc[i][j] = zero;

  // prologue: stage tile 0 (halves in order), wait half0, barrier
#pragma unroll
  for (int p = 0; p < 4; ++p)
    stage_pair(A, W, m0, n0, 0, As[0], Bs[0], wid, lm, quad, p);
  asm volatile("s_waitcnt vmcnt(4)" ::: "memory");
  asm volatile("s_barrier" ::: "memory");

#pragma unroll 1
  for (int t = 0; t < 16; ++t) {
    const int cur = t & 1;
    ushort_t* Ac = As[cur];
    ushort_t* Bc = Bs[cur];
    ushort_t* An = As[cur ^ 1];
    ushort_t* Bn = Bs[cur ^ 1];
    const int kn = (t + 1) << 6;
    const bool pf = (t < 15);

    bf16x8 a[4], b[4];

    // ---- phase 0: ks=0, mh=0 ----
#pragma unroll
    for (int i = 0; i < 4; ++i)
      a[i] = *(const bf16x8*)&Ac[((wm2 * 8 + i) * 2 + 0) * 512 + lane * 8];
#pragma unroll
    for (int j = 0; j < 4; ++j)
      b[j] = *(const bf16x8*)&Bc[((wn4 * 4 + j) * 2 + 0) * 512 + lane * 8];
    if (pf) stage_pair(A, W, m0, n0, kn, An, Bn, wid, lm, quad, 0);
    asm volatile("s_barrier" ::: "memory");
    __builtin_amdgcn_s_setprio(1);
#pragma unroll
    for (int i = 0; i < 4; ++i)
#pragma unroll
      for (int j = 0; j < 4; ++j)
        acc[i][j] = __builtin_amdgcn_mfma_f32_16x16x32_bf16(a[i], b[j], acc[i][j], 0, 0, 0);
    __builtin_amdgcn_s_setprio(0);
    asm volatile("s_barrier" ::: "memory");

    // ---- phase 1: ks=0, mh=1 (reuse b) ----
#pragma unroll
    for (int i = 0; i < 4; ++i)
      a[i] = *(const bf16x8*)&Ac[((wm2 * 8 + 4 + i) * 2 + 0) * 512 + lane * 8];
    if (pf) stage_pair(A, W, m0, n0, kn, An, Bn, wid, lm, quad, 1);
    asm volatile("s_barrier" ::: "memory");
    __builtin_amdgcn_s_setprio(1);
#pragma unroll
    for (int i = 0; i < 4; ++i)
#pragma unroll
      for (int j = 0; j < 4; ++j)
        acc[4 + i][j] = __builtin_amdgcn_mfma_f32_16x16x32_bf16(a[i], b[j], acc[4 + i][j], 0, 0, 0);
    __builtin_amdgcn_s_setprio(0);
    // guard cur.half1 for phases 2-3 (my oldest 4 = cur.half1's loads)
    if (pf) asm volatile("s_waitcnt vmcnt(4)" ::: "memory");
    else    asm volatile("s_waitcnt vmcnt(0)" ::: "memory");
    asm volatile("s_barrier" ::: "memory");

    // ---- phase 2: ks=1, mh=0 ----
#pragma unroll
    for (int i = 0; i < 4; ++i)
      a[i] = *(const bf16x8*)&Ac[((wm2 * 8 + i) * 2 + 1) * 512 + lane * 8];
#pragma unroll
    for (int j = 0; j < 4; ++j)
      b[j] = *(const bf16x8*)&Bc[((wn4 * 4 + j) * 2 + 1) * 512 + lane * 8];
    if (pf) stage_pair(A, W, m0, n0, kn, An, Bn, wid, lm, quad, 2);
    asm volatile("s_barrier" ::: "memory");
    __builtin_amdgcn_s_setprio(1);
#pragma unroll
    for (int i = 0; i < 4; ++i)
#pragma unroll
      for (int j = 0; j < 4; ++j)
        acc[i][j] = __builtin_amdgcn_mfma_f32_16x16x32_bf16(a[i], b[j], acc[i][j], 0, 0, 0);
    __builtin_amdgcn_s_setprio(0);
    asm volatile("s_barrier" ::: "memory");

    // ---- phase 3: ks=1, mh=1 (reuse b) ----
#pragma unroll
    for (int i = 0; i < 4; ++i)
      a[i] = *(const bf16x8*)&Ac[((wm2 * 8 + 4 + i) * 2 + 1) * 512 + lane * 8];
    if (pf) stage_pair(A, W, m0, n0, kn, An, Bn, wid, lm, quad, 3);
    asm volatile("s_barrier" ::: "memory");
    __builtin_amdgcn_s_setprio(1);
#pragma unroll
    for (int i = 0; i < 4; ++i)
#pragma unroll
      for (int j = 0; j < 4; ++j)
        acc[4 + i][j] = __builtin_amdgcn_mfma_f32_16x16x32_bf16(a[i], b[j], acc[4 + i][j], 0, 0, 0);
    __builtin_amdgcn_s_setprio(0);
    // guard next.half0 for next step's phases 0-1
    if (pf) asm volatile("s_waitcnt vmcnt(4)" ::: "memory");
    asm volatile("s_barrier" ::: "memory");
  }

#pragma unroll
  for (int i = 0; i < 8; ++i) {
    const int row = m0 + wm2 * 128 + i * 16 + quad * 4;
#pragma unroll
    for (int j = 0; j < 4; ++j)
      store_sub(Cv, mode, ldc, row, n0 + wn4 * 64 + j * 16 + lm, acc[i][j]);
  }
}

struct QkvArgs {
  const ushort_t* A[3];
  const ushort_t* W[3];
  char*           C[3];
};

// grid (16,4,3) = 192 blocks, single round on 256 CUs.
__global__ __launch_bounds__(512, 2) void qkv_gemm(QkvArgs q) {
  const int z = blockIdx.z;
  gemm512_8ph(q.A[z], q.W[z], q.C[z], z == 2 ? 2 : 0, EMBED,
              blockIdx.x * 256, blockIdx.y * 256);
}

// ---------------------------------------------------------------------------
// O-projection GEMM (r10): BM=128, BN=64, BK=64, 256 thr (4 waves 2m x 2n,
// each wave 64x32 = 4x2 subtiles).  Grid (32,16) = 512 blocks = 2 blocks/CU,
// 8 waves/CU in 2 independent barrier domains.  LDS 24KB.
// ---------------------------------------------------------------------------
__global__ __launch_bounds__(256, 4) void o_gemm(const ushort_t* __restrict__ A,
                                                 const ushort_t* __restrict__ W,
                                                 float* __restrict__ C) {
  __shared__ ushort_t As[16 * 512];   // 128 x 64, fragment-ordered
  __shared__ ushort_t Bs[8 * 512];    // 64 x 64
  const int m0 = blockIdx.x * 128, n0 = blockIdx.y * 64;
  const int tid  = threadIdx.x;
  const int lane = tid & 63;
  const int wid  = tid >> 6;          // 0..3
  const int lm   = lane & 15;
  const int quad = lane >> 4;
  const int wm   = wid >> 1;          // 0..1
  const int wn   = wid & 1;           // 0..1

  floatx4 zero = {0.f, 0.f, 0.f, 0.f};
  floatx4 acc[4][2];
#pragma unroll
  for (int i = 0; i < 4; ++i)
#pragma unroll
    for (int j = 0; j < 2; ++j) acc[i][j] = zero;

  for (int k0 = 0; k0 < EMBED; k0 += 64) {
    __syncthreads();
#pragma unroll
    for (int u = 0; u < 6; ++u) {
      const int c   = wid * 6 + u;     // 0..23, wave-uniform
      const int cb  = (c < 16) ? c : (c - 16);
      const int sub = cb >> 1;
      const int kc  = (cb & 1) * 32 + quad * 8;
      if (c < 16)
        gl_lds16(A + (size_t)(m0 + sub * 16 + lm) * EMBED + k0 + kc, &As[cb * 512]);
      else
        gl_lds16(W + (size_t)(n0 + sub * 16 + lm) * EMBED + k0 + kc, &Bs[cb * 512]);
    }
    __syncthreads();   // vmcnt drain -> LDS visible

#pragma unroll
    for (int ks = 0; ks < 2; ++ks) {
      bf16x8 a[4], b[2];
#pragma unroll
      for (int i = 0; i < 4; ++i)
        a[i] = *(const bf16x8*)&As[((wm * 4 + i) * 2 + ks) * 512 + lane * 8];
#pragma unroll
      for (int j = 0; j < 2; ++j)
        b[j] = *(const bf16x8*)&Bs[((wn * 2 + j) * 2 + ks) * 512 + lane * 8];
#pragma unroll
      for (int i = 0; i < 4; ++i)
#pragma unroll
        for (int j = 0; j < 2; ++j)
          acc[i][j] = __builtin_amdgcn_mfma_f32_16x16x32_bf16(a[i], b[j], acc[i][j], 0, 0, 0);
    }
  }

#pragma unroll
  for (int i = 0; i < 4; ++i) {
    const int row = m0 + wm * 64 + i * 16 + quad * 4;
#pragma unroll
    for (int j = 0; j < 2; ++j) {
      const int col = n0 + wn * 32 + j * 16 + lm;
#pragma unroll
      for (int r = 0; r < 4; ++r)
        C[(size_t)(row + r) * EMBED + col] = acc[i][j][r];
    }
  }
}

// ---------------------------------------------------------------------------
// Causal flash attention, S^T formulation, fixed-shift softmax, K/V dbuf.
// Grid 1024 x 256thr (4 waves).  Block = 64 q-cols of one (b,h); wave owns
// 16 q.  KT=64.  One barrier per iter; next K/V tile's global_load_lds
// issued right after the barrier, landing during compute.
// LDS 40KB -> 4 blocks/CU (16 waves/CU, 4/SIMD from 4 independent blocks).
// r19 qb map (long-with-long): slot s=(L>>5)&7, group g=L>>8:
//   {2s, 2s+1, 30-2s, 31-2s} -> the 4 blocks sharing a CU sum to 66 iters
// AND the two longest differ by 1 iter, so the tail runs 2 blocks (8 waves)
// instead of 1 (4 waves).  bh stays in L&31 -> same-head L2 pinning and
// 4-blocks-share-one-head preserved.
// ---------------------------------------------------------------------------
__global__ __launch_bounds__(256, 4) void attn_kernel(const ushort_t* __restrict__ Qp,
                                                      const ushort_t* __restrict__ Kp,
                                                      const ushort_t* __restrict__ VpT,
                                                      ushort_t* __restrict__ Ob) {
  __shared__ ushort_t Qs[8 * 512];       // 64 q x 64 d; aliased as P scratch
  __shared__ ushort_t Ks[2][8 * 512];    // dbuf: 64 kk x 64 d
  __shared__ ushort_t VTs[2][8 * 512];   // dbuf: 64 d x 64 kk
  const int L = blockIdx.x;              // 0..1023
  const int s8 = (L >> 5) & 7;
  const int g  = L >> 8;                 // 0..3
  const int qb = (g == 0) ? (2 * s8)
               : (g == 1) ? (2 * s8 + 1)
               : (g == 2) ? (30 - 2 * s8)
                          : (31 - 2 * s8);
  const int bh = L & 31;
  const int h = bh & (NH - 1), b = bh >> 4;
  const int tid = threadIdx.x, lane = tid & 63, wid = tid >> 6;
  const int lm = lane & 15, quad = lane >> 4;
  const size_t qkbase = ((size_t)b * SEQ) * EMBED + h * DH;
  const size_t vtbase = ((size_t)(b * NH + h)) * DH * SEQ;

  // Q staging: 4 chunks of 512; wave's pair c = wid*2 + u covers its 16 q.
#pragma unroll
  for (int u = 0; u < 2; ++u) {
    const int c = wid * 2 + u;
    gl_lds16(Qp + qkbase + (size_t)(qb * 64 + (c >> 1) * 16 + lm) * EMBED
                 + (c & 1) * 32 + quad * 8,
             &Qs[c * 512]);
  }
  // issue K/V for kt=0 into buf 0 (behind the Q loads)
#pragma unroll
  for (int u = 0; u < 4; ++u) {
    const int t = wid * 4 + u;
    const int cb = t & 7, sub = cb >> 1, half = cb & 1;
    if (t < 8)
      gl_lds16(Kp + qkbase + (size_t)(sub * 16 + lm) * EMBED + half * 32 + quad * 8,
               &Ks[0][cb * 512]);
    else
      gl_lds16(VpT + vtbase + (size_t)(sub * 16 + lm) * SEQ + half * 32 + quad * 8,
               &VTs[0][cb * 512]);
  }
  asm volatile("s_waitcnt vmcnt(4)" ::: "memory");   // my Q chunks landed
  bf16x8 qf[2];   // [ks]
#pragma unroll
  for (int ks = 0; ks < 2; ++ks)
    qf[ks] = *(const bf16x8*)&Qs[(wid * 2 + ks) * 512 + lane * 8];
  // Q region is now dead; reuse the wave's own 2KB slice as P scratch.
  ushort_t* pwb = &Qs[wid * 1024];

  float l_part = 0.f;
  floatx4 zero = {0.f, 0.f, 0.f, 0.f};
  floatx4 o_acc[4];
#pragma unroll
  for (int d = 0; d < 4; ++d) o_acc[d] = zero;

  for (int kt = 0; kt <= qb; ++kt) {
    const int cur = kt & 1;
    // my K/V[cur] loads (issued last iter / preamble) have landed by now
    asm volatile("s_waitcnt vmcnt(0)" ::: "memory");
    __syncthreads();   // all waves' cur loads landed; all done reading buf cur^1
    if (kt < qb) {
      const int kn = kt + 1;
#pragma unroll
      for (int u = 0; u < 4; ++u) {
        const int t = wid * 4 + u;
        const int cb = t & 7, sub = cb >> 1, half = cb & 1;
        if (t < 8)
          gl_lds16(Kp + qkbase + (size_t)(kn * 64 + sub * 16 + lm) * EMBED
                       + half * 32 + quad * 8,
                   &Ks[cur ^ 1][cb * 512]);
        else
          gl_lds16(VpT + vtbase + (size_t)(sub * 16 + lm) * SEQ
                       + kn * 64 + half * 32 + quad * 8,
                   &VTs[cur ^ 1][cb * 512]);
      }
    }

    // S^T = K Q^T (log2e domain): s_acc[i], i = kk-subtile 0..3
    floatx4 s_acc[4];
#pragma unroll
    for (int i = 0; i < 4; ++i) s_acc[i] = zero;
#pragma unroll
    for (int ks = 0; ks < 2; ++ks)
#pragma unroll
      for (int i = 0; i < 4; ++i) {
        bf16x8 kf = *(const bf16x8*)&Ks[cur][(i * 2 + ks) * 512 + lane * 8];
        s_acc[i] = __builtin_amdgcn_mfma_f32_16x16x32_bf16(kf, qf[ks], s_acc[i], 0, 0, 0);
      }

    // exp2, diagonal mask, l accumulate, pack P^T into wave-private scratch
    const bool diag = (kt == qb);   // uniform branch; last iter only
#pragma unroll
    for (int i = 0; i < 4; ++i) {
      const int sH = i >> 1;
      const int quadB = ((i & 1) << 1) | (quad >> 1);
      const int gkk = kt * 64 + i * 16 + quad * 4;
      float p[4];
#pragma unroll
      for (int r = 0; r < 4; ++r) p[r] = __builtin_amdgcn_exp2f(s_acc[i][r]);
      if (diag) {
        const int gq = qb * 64 + wid * 16 + lm;
#pragma unroll
        for (int r = 0; r < 4; ++r)
          if (gkk + r > gq) p[r] = 0.f;
      }
#pragma unroll
      for (int r = 0; r < 4; ++r) l_part += p[r];
      uint2 pk;
      pk.x = pk2(p[0], p[1]);
      pk.y = pk2(p[2], p[3]);
      *(uint2*)&pwb[sH * 512 + (quadB * 16 + lm) * 8 + ((quad & 1) << 2)] = pk;
    }
    asm volatile("s_waitcnt lgkmcnt(0)" ::: "memory");   // wave-local RAW fence

    // O^T += V^T P^T
#pragma unroll
    for (int sH = 0; sH < 2; ++sH) {
      bf16x8 pf = *(const bf16x8*)&pwb[sH * 512 + lane * 8];
#pragma unroll
      for (int d = 0; d < 4; ++d) {
        bf16x8 vf = *(const bf16x8*)&VTs[cur][(d * 2 + sH) * 512 + lane * 8];
        o_acc[d] = __builtin_amdgcn_mfma_f32_16x16x32_bf16(vf, pf, o_acc[d], 0, 0, 0);
      }
    }
  }

  // epilogue
  {
    float l = l_part;
    l += __shfl_xor(l, 16, 64);
    l += __shfl_xor(l, 32, 64);
    const float inv_l = 1.0f / l;
    const size_t orow = qkbase + (size_t)(qb * 64 + wid * 16 + lm) * EMBED;
#pragma unroll
    for (int d = 0; d < 4; ++d) {
      uint2 pk;
      pk.x = pk2(o_acc[d][0] * inv_l, o_acc[d][1] * inv_l);
      pk.y = pk2(o_acc[d][2] * inv_l, o_acc[d][3] * inv_l);
      *(uint2*)&Ob[orow + d * 16 + quad * 4] = pk;
    }
  }
}

// ---------------------------------------------------------------------------
// launch
// ---------------------------------------------------------------------------
extern "C" void kernel_launch(void* const* d_in, const int* in_sizes, int n_in,
                              void* d_out, int out_size, void* d_ws, size_t ws_size,
                              hipStream_t stream) {
  // setup_inputs() order: key, query, value, mask, Wq, Wk, Wv, Wo
  const float* key   = (const float*)d_in[0];
  const float* query = (const float*)d_in[1];
  const float* value = (const float*)d_in[2];
  // d_in[3] = static causal tril, handled analytically
  const float* Wq = (const float*)d_in[4];
  const float* Wk = (const float*)d_in[5];
  const float* Wv = (const float*)d_in[6];
  const float* Wo = (const float*)d_in[7];

  char* ws = (char*)d_ws;
  const size_t MB = 1024 * 1024;
  ushort_t* Xk  = (ushort_t*)(ws + 0 * MB);    // key   bf16 [4096][1024]
  ushort_t* Xq  = (ushort_t*)(ws + 8 * MB);    // query bf16
  ushort_t* Xv  = (ushort_t*)(ws + 16 * MB);   // value bf16
  ushort_t* Wqb = (ushort_t*)(ws + 24 * MB);   // pre-scaled by 0.125*log2e
  ushort_t* Wkb = (ushort_t*)(ws + 26 * MB);
  ushort_t* Wvb = (ushort_t*)(ws + 28 * MB);
  ushort_t* Wob = (ushort_t*)(ws + 30 * MB);
  ushort_t* Qp  = (ushort_t*)(ws + 32 * MB);   // projected Q (log2e-scaled)
  ushort_t* Kp  = (ushort_t*)(ws + 40 * MB);
  ushort_t* VpT = (ushort_t*)(ws + 48 * MB);   // [b][h][64][2048]
  ushort_t* Ob  = (ushort_t*)(ws + 56 * MB);   // attention out bf16

  CvtArgs ca;
  const size_t CE = 1048576;
  for (int c = 0; c < 16; ++c) ca.scale[c] = 1.0f;
  for (int c = 0; c < 4; ++c) { ca.src[c]     = key   + c * CE; ca.dst[c]     = Xk + c * CE; }
  for (int c = 0; c < 4; ++c) { ca.src[4 + c] = query + c * CE; ca.dst[4 + c] = Xq + c * CE; }
  for (int c = 0; c < 4; ++c) { ca.src[8 + c] = value + c * CE; ca.dst[8 + c] = Xv + c * CE; }
  ca.src[12] = Wq; ca.dst[12] = Wqb; ca.scale[12] = QK_SCALE;
  ca.src[13] = Wk; ca.dst[13] = Wkb;
  ca.src[14] = Wv; ca.dst[14] = Wvb;
  ca.src[15] = Wo; ca.dst[15] = Wob;
  cvt_kernel<<<8192, 256, 0, stream>>>(ca);

  QkvArgs qa;
  qa.A[0] = Xq; qa.W[0] = Wqb; qa.C[0] = (char*)Qp;
  qa.A[1] = Xk; qa.W[1] = Wkb; qa.C[1] = (char*)Kp;
  qa.A[2] = Xv; qa.W[2] = Wvb; qa.C[2] = (char*)VpT;   // z=2 writes transposed
  qkv_gemm<<<dim3(16, 4, 3), 512, 0, stream>>>(qa);

  attn_kernel<<<1024, 256, 0, stream>>>(Qp, Kp, VpT, Ob);

  o_gemm<<<dim3(32, 16), 256, 0, stream>>>(Ob, Wob, (float*)d_out);
}